// Round 11
// baseline (1814.015 us; speedup 1.0000x reference)
//
#include <hip/hip_runtime.h>

typedef __attribute__((ext_vector_type(8))) _Float16 f16x8;
typedef __attribute__((ext_vector_type(4))) float f32x4;

#define DEVINL __device__ __forceinline__

constexpr int BATCH = 16384;
constexpr int DIN   = 1024;
constexpr int DHID  = 2048;
constexpr int NEXP  = 16;
constexpr int EXPSZ = 512;
constexpr int NPAIR = BATCH * 3;

DEVINL unsigned short f2h(float v) {
  _Float16 h = (_Float16)v;
  return __builtin_bit_cast(unsigned short, h);
}
DEVINL float h2f(unsigned short u) {
  return (float)__builtin_bit_cast(_Float16, u);
}

DEVINL void gl2lds(const unsigned short* src, char* ldst) {
  __builtin_amdgcn_global_load_lds((const __attribute__((address_space(1))) void*)src,
                                   (__attribute__((address_space(3))) void*)ldst, 16, 0, 0);
}

// ---------------------------------------------------------------------------
// fp16 split-MFMA GEMM, 128x128 tile, 4 waves (2x2 of 64x64), 16x16x32 f16.
// Operands staged via global_load_lds (fragment-contiguous LDS). 1D grid
// (x = NXT*NYT tiles, z = expert); row-tiles round-robined across XCDs,
// col-tiles consecutive within an XCD (load-balanced under early-exit +
// A-panel L2 reuse; bijective for NXT%8==0 — speed-only).
// SPLIT=1: v = c0 + c1/2048 (c1 stored x2048). 3 MFMA terms. SPLIT=0: fp16.
// AMODE: 0 linear A rows; 1 gather via pairRow; 2 pair-linear.
// TASK:  bias += (*taskPtr)*N (task-indexed tower bias; B pre-extracted).
// EPI:   0 +bias -> fp16 hi/lo pair; 1 +bias,relu -> fp16;
//        2 +bias,*pairW -> fp16; 3 +bias -> fp32.
// ---------------------------------------------------------------------------
template<int SPLIT, int AMODE, int EPI, int BK, int NYT, int TASK>
__global__ __launch_bounds__(256, 3)
void mgemm_k(const unsigned short* __restrict__ A0p,
             const unsigned short* __restrict__ A1p,
             const unsigned short* __restrict__ B0p,
             const unsigned short* __restrict__ B1p,
             const float* __restrict__ biasb,
             float* __restrict__ Cf, unsigned short* __restrict__ Cb0,
             unsigned short* __restrict__ Cb1,
             const int* __restrict__ pairRow, const float* __restrict__ pairW,
             const int* __restrict__ counts, const int* __restrict__ offs,
             const int* __restrict__ taskPtr,
             int M, int N, int K)
{
  constexpr int KG = BK / 8;
  constexpr int UNITS = 128 * KG;
  constexpr int ISS = UNITS / 256;
  constexpr int NKK = BK / 32;
  constexpr int NARR = SPLIT ? 4 : 2;
  constexpr bool EXPERT = (AMODE == 1 || AMODE == 2);
  __shared__ char smem[NARR * UNITS * 16];
  char* sA0 = smem;
  char* sA1 = smem + UNITS * 16;                    // iff SPLIT
  char* sB0 = smem + (SPLIT ? 2 : 1) * UNITS * 16;
  char* sB1 = smem + 3 * UNITS * 16;                // iff SPLIT

  int Mloc = M, rowBase = 0;
  const unsigned short* b0 = B0p;
  const unsigned short* b1 = B1p;
  const float* bias = biasb;
  if (EXPERT) {
    const int e = blockIdx.z;
    Mloc = counts[e];
    rowBase = offs[e];
    const size_t eo = (size_t)e * (size_t)K * N;
    b0 = B0p + eo;
    if (SPLIT) b1 = B1p + eo;
    bias = biasb + (size_t)e * N;
  }
  if (TASK) bias = biasb + (size_t)(*taskPtr) * N;

  // round-robin row-tiles over XCDs; col-tiles consecutive within XCD
  const int xcd = (int)blockIdx.x & 7;
  const int j   = (int)blockIdx.x >> 3;
  const int tile0 = (xcd + 8 * (j / NYT)) * 128;
  const int col0  = (j % NYT) * 128;
  if (tile0 >= Mloc) return;

  const int tid = threadIdx.x;
  const int lane = tid & 63;
  const int wr = ((tid >> 6) >> 1) * 64;
  const int wc = ((tid >> 6) & 1) * 64;
  const int l15 = lane & 15;
  const int lg = lane >> 4;

  // per-thread staging row (fixed across K)
  const int srow = tid & 127;
  size_t aoff;
  if (AMODE == 0) {
    aoff = (size_t)(tile0 + srow) * K;
  } else if (AMODE == 1) {
    int p = rowBase + tile0 + srow; p = p < NPAIR - 1 ? p : NPAIR - 1;
    aoff = (size_t)pairRow[p] * K;
  } else {
    int p = rowBase + tile0 + srow; p = p < NPAIR - 1 ? p : NPAIR - 1;
    aoff = (size_t)p * K;
  }
  const size_t boff = (size_t)(col0 + srow) * K;

  f32x4 acc[4][4];
  f32x4 acc2[4][4];
  #pragma unroll
  for (int m = 0; m < 4; ++m)
    #pragma unroll
    for (int n = 0; n < 4; ++n) {
      acc[m][n] = f32x4{0.f, 0.f, 0.f, 0.f};
      if (SPLIT) acc2[m][n] = f32x4{0.f, 0.f, 0.f, 0.f};
    }

  for (int kt = 0; kt < K; kt += BK) {
    #pragma unroll
    for (int it = 0; it < ISS; ++it) {
      const int uo = (it * 256 + (tid & 192)) * 16;   // wave-uniform LDS base
      const int ko = kt + (it * 2 + (tid >> 7)) * 8;
      gl2lds(A0p + aoff + ko, sA0 + uo);
      if (SPLIT) gl2lds(A1p + aoff + ko, sA1 + uo);
      gl2lds(b0 + boff + ko, sB0 + uo);
      if (SPLIT) gl2lds(b1 + boff + ko, sB1 + uo);
    }
    __syncthreads();
    #pragma unroll
    for (int kk = 0; kk < NKK; ++kk) {
      const int g = kk * 4 + lg;
      f16x8 b0f[4], b1f[4];
      #pragma unroll
      for (int n = 0; n < 4; ++n) {
        const size_t off = (size_t)(g * 128 + wc + n * 16 + l15) * 16;
        b0f[n] = *(const f16x8*)(sB0 + off);
        if (SPLIT) b1f[n] = *(const f16x8*)(sB1 + off);
      }
      #pragma unroll
      for (int m = 0; m < 4; ++m) {
        const size_t ao = (size_t)(g * 128 + wr + m * 16 + l15) * 16;
        const f16x8 a0 = *(const f16x8*)(sA0 + ao);
        f16x8 a1;
        if (SPLIT) a1 = *(const f16x8*)(sA1 + ao);
        #pragma unroll
        for (int n = 0; n < 4; ++n) {
          if (SPLIT) {
            acc2[m][n] = __builtin_amdgcn_mfma_f32_16x16x32_f16(a1, b0f[n], acc2[m][n], 0, 0, 0);
            acc2[m][n] = __builtin_amdgcn_mfma_f32_16x16x32_f16(a0, b1f[n], acc2[m][n], 0, 0, 0);
          }
          acc[m][n] = __builtin_amdgcn_mfma_f32_16x16x32_f16(a0, b0f[n], acc[m][n], 0, 0, 0);
        }
      }
    }
    __syncthreads();
  }

  // epilogue. C/D mapping: col = lane&15, row = (lane>>4)*4 + j  [m89-verified]
  #pragma unroll
  for (int n = 0; n < 4; ++n) {
    const int cn = col0 + wc + n * 16 + l15;
    const float bv = bias[cn];
    #pragma unroll
    for (int m = 0; m < 4; ++m) {
      const int r0 = wr + m * 16 + ((lane >> 4) << 2);
      #pragma unroll
      for (int jj = 0; jj < 4; ++jj) {
        const int rm = tile0 + r0 + jj;
        if (EXPERT && rm >= Mloc) continue;
        float v = acc[m][n][jj];
        if (SPLIT) v += acc2[m][n][jj] * (1.f / 2048.f);
        v += bv;
        const size_t ci = (size_t)(EXPERT ? (rowBase + rm) : rm) * N + cn;
        if (EPI == 0) {
          const unsigned short h0 = f2h(v);
          Cb0[ci] = h0;
          Cb1[ci] = f2h((v - h2f(h0)) * 2048.f);
        } else if (EPI == 1) {
          Cb0[ci] = f2h(fmaxf(v, 0.f));
        } else if (EPI == 2) {
          Cb0[ci] = f2h(v * pairW[rowBase + rm]);
        } else {
          Cf[ci] = v;
        }
      }
    }
  }
}

// ---------------------------------------------------------------------------
// fp32 vector GEMM (gate). C = relu(A@B[t] + bias[t]), fp32.
// ---------------------------------------------------------------------------
template<bool RELU>
__global__ __launch_bounds__(256, 2)
void gemm32_k(const float* __restrict__ Av, const float* __restrict__ Bb,
              const float* __restrict__ biasb, float* __restrict__ Cv,
              const int* __restrict__ taskPtr, int M, int N, int K)
{
  __shared__ float As[16][128];
  __shared__ float Bs[16][128];
  const int t = *taskPtr;
  const float* Bw = Bb + (size_t)t * K * N;
  const float* bias = biasb + (size_t)t * N;
  const int tile0 = blockIdx.x * 128;
  const int col0 = blockIdx.y * 128;
  const int tid = threadIdx.x;
  const int am = tid >> 1, ak = (tid & 1) * 8;
  const int bk = tid >> 4, bn = (tid & 15) * 8;
  const int rg = (tid >> 4) * 8, cg = (tid & 15) * 8;
  const float* aptr = Av + (size_t)(tile0 + am) * K;

  float acc[8][8];
  #pragma unroll
  for (int i = 0; i < 8; ++i)
    #pragma unroll
    for (int j = 0; j < 8; ++j) acc[i][j] = 0.f;

  for (int kt = 0; kt < K; kt += 16) {
    {
      const float* src = aptr + kt + ak;
      float4 x0 = *reinterpret_cast<const float4*>(src);
      float4 x1 = *reinterpret_cast<const float4*>(src + 4);
      As[ak+0][am]=x0.x; As[ak+1][am]=x0.y; As[ak+2][am]=x0.z; As[ak+3][am]=x0.w;
      As[ak+4][am]=x1.x; As[ak+5][am]=x1.y; As[ak+6][am]=x1.z; As[ak+7][am]=x1.w;
    }
    {
      const float* bsrc = Bw + (size_t)(kt + bk) * N + (col0 + bn);
      float4 b0 = *reinterpret_cast<const float4*>(bsrc);
      float4 b1 = *reinterpret_cast<const float4*>(bsrc + 4);
      Bs[bk][bn+0]=b0.x; Bs[bk][bn+1]=b0.y; Bs[bk][bn+2]=b0.z; Bs[bk][bn+3]=b0.w;
      Bs[bk][bn+4]=b1.x; Bs[bk][bn+5]=b1.y; Bs[bk][bn+6]=b1.z; Bs[bk][bn+7]=b1.w;
    }
    __syncthreads();
    #pragma unroll
    for (int k = 0; k < 16; ++k) {
      float4 a0 = *reinterpret_cast<const float4*>(&As[k][rg]);
      float4 a1 = *reinterpret_cast<const float4*>(&As[k][rg + 4]);
      float4 c0 = *reinterpret_cast<const float4*>(&Bs[k][cg]);
      float4 c1 = *reinterpret_cast<const float4*>(&Bs[k][cg + 4]);
      const float a[8] = {a0.x,a0.y,a0.z,a0.w,a1.x,a1.y,a1.z,a1.w};
      const float b[8] = {c0.x,c0.y,c0.z,c0.w,c1.x,c1.y,c1.z,c1.w};
      #pragma unroll
      for (int i = 0; i < 8; ++i)
        #pragma unroll
        for (int j = 0; j < 8; ++j)
          acc[i][j] = fmaf(a[i], b[j], acc[i][j]);
    }
    __syncthreads();
  }
  #pragma unroll
  for (int i = 0; i < 8; ++i) {
    const int mr = tile0 + rg + i;
    #pragma unroll
    for (int j = 0; j < 8; ++j) {
      float v = acc[i][j] + bias[col0 + cg + j];
      if (RELU) v = fmaxf(v, 0.f);
      Cv[(size_t)mr * N + col0 + cg + j] = v;
    }
  }
}

// ---------------------------------------------------------------------------
// transpose+convert: src fp32 [z][R][C] -> fp16 level arrays [z][C][R].
// LEV=2: level-1 stored x2048. TASK: src += (*taskPtr)*R*C (extract task t).
// ---------------------------------------------------------------------------
template<int LEV, int TASK>
__global__ __launch_bounds__(256)
void transp_k(const float* __restrict__ src, unsigned short* __restrict__ d0,
              unsigned short* __restrict__ d1, const int* __restrict__ taskPtr,
              int R, int C)
{
  __shared__ float tle[32][33];
  size_t bb = (size_t)blockIdx.z * R * C;
  if (TASK) bb = (size_t)(*taskPtr) * R * C;
  const int r0 = blockIdx.x * 32, c0 = blockIdx.y * 32;
  const int x = threadIdx.x & 31, y = threadIdx.x >> 5;
  #pragma unroll
  for (int i = 0; i < 32; i += 8)
    tle[y + i][x] = src[bb + (size_t)(r0 + y + i) * C + (c0 + x)];
  __syncthreads();
  const size_t db = TASK ? 0 : (size_t)blockIdx.z * R * C;
  #pragma unroll
  for (int i = 0; i < 32; i += 8) {
    const float v = tle[x][y + i];
    const size_t di = db + (size_t)(c0 + y + i) * R + (r0 + x);
    const unsigned short h0 = f2h(v);
    d0[di] = h0;
    if (LEV > 1) d1[di] = f2h((v - h2f(h0)) * 2048.f);
  }
}

// concat(embP,embR) fp32 -> fp16 hi/lo pair arrays [B][1024]
__global__ __launch_bounds__(256)
void convx_k(const float* __restrict__ eP, const float* __restrict__ eR,
             unsigned short* __restrict__ x0, unsigned short* __restrict__ x1)
{
  const size_t u = (size_t)blockIdx.x * 256 + threadIdx.x;  // 4-elem units
  const size_t row = u >> 8;
  const int c4 = (int)(u & 255) * 4;
  const float* s = (c4 < 512) ? (eP + row * 512 + c4) : (eR + row * 512 + (c4 - 512));
  const float4 v = *(const float4*)s;
  const float vv[4] = {v.x, v.y, v.z, v.w};
  ushort4 h4, l4;
  unsigned short* hp = (unsigned short*)&h4;
  unsigned short* lp = (unsigned short*)&l4;
  #pragma unroll
  for (int j = 0; j < 4; ++j) {
    const unsigned short h0 = f2h(vv[j]);
    hp[j] = h0;
    lp[j] = f2h((vv[j] - h2f(h0)) * 2048.f);
  }
  *(ushort4*)(x0 + row * 1024 + c4) = h4;
  *(ushort4*)(x1 + row * 1024 + c4) = l4;
}

// ---------------------------------------------------------------------------
// In-place LayerNorm + relu over fp16 hi/lo pair rows (fp32 math).
// ---------------------------------------------------------------------------
template<int COLS, bool RELU>
__global__ __launch_bounds__(256)
void ln_pair_k(unsigned short* __restrict__ h0, unsigned short* __restrict__ h1,
               const float* __restrict__ g, const float* __restrict__ b)
{
  constexpr int PER = COLS / 256;
  const size_t row = blockIdx.x;
  unsigned short* r0 = h0 + row * COLS;
  unsigned short* r1 = h1 + row * COLS;
  const int c0 = threadIdx.x * PER;
  float v[PER];
  float s = 0.f, s2 = 0.f;
  #pragma unroll
  for (int i = 0; i < PER; i += 4) {
    const ushort4 a = *(const ushort4*)(r0 + c0 + i);
    const ushort4 c = *(const ushort4*)(r1 + c0 + i);
    v[i+0] = h2f(a.x) + h2f(c.x) * (1.f/2048.f);
    v[i+1] = h2f(a.y) + h2f(c.y) * (1.f/2048.f);
    v[i+2] = h2f(a.z) + h2f(c.z) * (1.f/2048.f);
    v[i+3] = h2f(a.w) + h2f(c.w) * (1.f/2048.f);
  }
  #pragma unroll
  for (int i = 0; i < PER; ++i) { s += v[i]; s2 += v[i] * v[i]; }
  #pragma unroll
  for (int o = 1; o < 64; o <<= 1) { s += __shfl_xor(s, o); s2 += __shfl_xor(s2, o); }
  __shared__ float ss[4], ss2[4];
  const int w = threadIdx.x >> 6;
  if ((threadIdx.x & 63) == 0) { ss[w] = s; ss2[w] = s2; }
  __syncthreads();
  s  = ss[0] + ss[1] + ss[2] + ss[3];
  s2 = ss2[0] + ss2[1] + ss2[2] + ss2[3];
  const float mu = s * (1.f / COLS);
  const float var = s2 * (1.f / COLS) - mu * mu;
  const float rs = rsqrtf(var + 1e-5f);
  #pragma unroll
  for (int i = 0; i < PER; i += 4) {
    ushort4 a4, c4v;
    unsigned short* ap = (unsigned short*)&a4;
    unsigned short* cp = (unsigned short*)&c4v;
    #pragma unroll
    for (int j = 0; j < 4; ++j) {
      const int c = c0 + i + j;
      float y = (v[i+j] - mu) * rs * g[c] + b[c];
      if (RELU) y = fmaxf(y, 0.f);
      const unsigned short hh = f2h(y);
      ap[j] = hh;
      cp[j] = f2h((y - h2f(hh)) * 2048.f);
    }
    *(ushort4*)(r0 + c0 + i) = a4;
    *(ushort4*)(r1 + c0 + i) = c4v;
  }
}

// ---------------------------------------------------------------------------
// In-place LayerNorm over fp32 rows; optionally also emit fp16 mirror.
// ---------------------------------------------------------------------------
template<int COLS, bool RELU, bool F16OUT>
__global__ __launch_bounds__(256)
void ln_k(float* __restrict__ x, const float* __restrict__ g, const float* __restrict__ b,
          unsigned short* __restrict__ x16)
{
  constexpr int PER = COLS / 256;
  const size_t row = blockIdx.x;
  float* xr = x + row * COLS;
  float v[PER];
  float s = 0.f, s2 = 0.f;
  #pragma unroll
  for (int i = 0; i < PER; ++i) {
    v[i] = xr[threadIdx.x + i * 256];
    s += v[i];
    s2 += v[i] * v[i];
  }
  #pragma unroll
  for (int o = 1; o < 64; o <<= 1) { s += __shfl_xor(s, o); s2 += __shfl_xor(s2, o); }
  __shared__ float ss[4], ss2[4];
  const int w = threadIdx.x >> 6;
  if ((threadIdx.x & 63) == 0) { ss[w] = s; ss2[w] = s2; }
  __syncthreads();
  s  = ss[0] + ss[1] + ss[2] + ss[3];
  s2 = ss2[0] + ss2[1] + ss2[2] + ss2[3];
  const float mu = s * (1.f / COLS);
  const float var = s2 * (1.f / COLS) - mu * mu;
  const float rs = rsqrtf(var + 1e-5f);
  #pragma unroll
  for (int i = 0; i < PER; ++i) {
    const int c = threadIdx.x + i * 256;
    float y = (v[i] - mu) * rs * g[c] + b[c];
    if (RELU) y = fmaxf(y, 0.f);
    xr[c] = y;
    if (F16OUT) x16[row * COLS + c] = f2h(y);
  }
}

// ---------------------------------------------------------------------------
// gate: logits = relu-g @ gW2[t] + gb2[t]; top-3 softmax; NO global atomics.
// ---------------------------------------------------------------------------
__global__ __launch_bounds__(256)
void gate_topk_k(const float* __restrict__ g, const float* __restrict__ gW2,
                 const float* __restrict__ gb2, const int* __restrict__ taskPtr,
                 float* __restrict__ gatesOut, int* __restrict__ topkIdx,
                 float* __restrict__ topkW)
{
  const int t = *taskPtr;
  const float* W = gW2 + (size_t)t * 128 * 16;
  const float* bias = gb2 + (size_t)t * 16;
  const int lane = threadIdx.x & 63;
  const int row = blockIdx.x * 4 + (threadIdx.x >> 6);
  const float* gr = g + (size_t)row * 128;
  const int e = lane & 15;
  const int q = lane >> 4;
  float s = 0.f;
  for (int j = q * 32; j < q * 32 + 32; ++j) s = fmaf(gr[j], W[j * 16 + e], s);
  s += __shfl_xor(s, 16);
  s += __shfl_xor(s, 32);
  s += bias[e];
  float logits[16];
  #pragma unroll
  for (int i = 0; i < 16; ++i) logits[i] = __shfl(s, i);
  int i0 = 0; float v0 = logits[0];
  #pragma unroll
  for (int i = 1; i < 16; ++i) if (logits[i] > v0) { v0 = logits[i]; i0 = i; }
  int i1 = -1; float v1 = -3.4e38f;
  #pragma unroll
  for (int i = 0; i < 16; ++i) if (i != i0 && logits[i] > v1) { v1 = logits[i]; i1 = i; }
  int i2 = -1; float v2 = -3.4e38f;
  #pragma unroll
  for (int i = 0; i < 16; ++i) if (i != i0 && i != i1 && logits[i] > v2) { v2 = logits[i]; i2 = i; }
  const float ex1 = expf(v1 - v0);
  const float ex2 = expf(v2 - v0);
  const float inv = 1.f / (1.f + ex1 + ex2);
  const float p0 = inv, p1 = ex1 * inv, p2 = ex2 * inv;
  if (lane < 16) {
    const float gv = (lane == i0) ? p0 : (lane == i1) ? p1 : (lane == i2) ? p2 : 0.f;
    gatesOut[(size_t)row * 16 + lane] = gv;
  }
  if (lane == 0) {
    topkIdx[row * 3 + 0] = i0; topkIdx[row * 3 + 1] = i1; topkIdx[row * 3 + 2] = i2;
    topkW [row * 3 + 0] = p0; topkW [row * 3 + 1] = p1; topkW [row * 3 + 2] = p2;
  }
}

// per-chunk expert histogram (LDS atomics only)
__global__ __launch_bounds__(256)
void hist_k(const int* __restrict__ topkIdx, int* __restrict__ chunkCnt)
{
  __shared__ int lc[NEXP];
  if (threadIdx.x < NEXP) lc[threadIdx.x] = 0;
  __syncthreads();
  const int row = blockIdx.x * 256 + threadIdx.x;
  #pragma unroll
  for (int k = 0; k < 3; ++k) atomicAdd(&lc[topkIdx[row * 3 + k]], 1);
  __syncthreads();
  if (threadIdx.x < NEXP) chunkCnt[blockIdx.x * NEXP + threadIdx.x] = lc[threadIdx.x];
}

// serial scan: counts/offs per expert + per-chunk bases
__global__ void scanB_k(const int* __restrict__ chunkCnt, int* __restrict__ counts,
                        int* __restrict__ offs, int* __restrict__ chunkBase)
{
  if (threadIdx.x == 0) {
    int tot[NEXP];
    for (int e = 0; e < NEXP; ++e) tot[e] = 0;
    for (int c = 0; c < 64; ++c)
      for (int e = 0; e < NEXP; ++e) tot[e] += chunkCnt[c * NEXP + e];
    int a = 0;
    for (int e = 0; e < NEXP; ++e) { offs[e] = a; counts[e] = tot[e]; a += tot[e]; }
    for (int e = 0; e < NEXP; ++e) {
      int b = offs[e];
      for (int c = 0; c < 64; ++c) { chunkBase[c * NEXP + e] = b; b += chunkCnt[c * NEXP + e]; }
    }
  }
}

// fill pair lists: LDS-atomic within-chunk offsets + precomputed chunk base
__global__ __launch_bounds__(256)
void fill2_k(const int* __restrict__ topkIdx, const float* __restrict__ topkW,
             const int* __restrict__ chunkBase, int* __restrict__ pairRow,
             float* __restrict__ pairW, int* __restrict__ rowPos)
{
  __shared__ int lc[NEXP];
  if (threadIdx.x < NEXP) lc[threadIdx.x] = 0;
  __syncthreads();
  const int row = blockIdx.x * 256 + threadIdx.x;
  #pragma unroll
  for (int k = 0; k < 3; ++k) {
    const int e = topkIdx[row * 3 + k];
    const int lofs = atomicAdd(&lc[e], 1);
    const int pos = chunkBase[blockIdx.x * NEXP + e] + lofs;
    pairRow[pos] = row;
    pairW[pos] = topkW[row * 3 + k];
    rowPos[row * 3 + k] = pos;
  }
}

// mix (fp16 out) = sum of the row's 3 eo slots
__global__ __launch_bounds__(256)
void mixreduce_k(const unsigned short* __restrict__ eo, const int* __restrict__ rowPos,
                 unsigned short* __restrict__ mix16)
{
  const size_t row = blockIdx.x;
  const size_t p0 = rowPos[row * 3 + 0];
  const size_t p1 = rowPos[row * 3 + 1];
  const size_t p2 = rowPos[row * 3 + 2];
  for (int c = threadIdx.x; c < EXPSZ; c += 256) {
    mix16[row * EXPSZ + c] = f2h(h2f(eo[p0 * EXPSZ + c]) + h2f(eo[p1 * EXPSZ + c])
                               + h2f(eo[p2 * EXPSZ + c]));
  }
}

__global__ __launch_bounds__(256)
void tower3_k(const unsigned short* __restrict__ t2, const float* __restrict__ tW3,
              const float* __restrict__ tb3, const int* __restrict__ taskPtr,
              float* __restrict__ out)
{
  const int t = *taskPtr;
  const float* w = tW3 + (size_t)t * 128;
  const float bias = tb3[t];
  const int lane = threadIdx.x & 63;
  const int row = blockIdx.x * 4 + (threadIdx.x >> 6);
  const unsigned short* x = t2 + (size_t)row * 128;
  float s = fmaf(h2f(x[lane]), w[lane], h2f(x[lane + 64]) * w[lane + 64]);
  #pragma unroll
  for (int o = 1; o < 64; o <<= 1) s += __shfl_xor(s, o);
  if (lane == 0) out[row] = 1.f / (1.f + expf(-(s + bias)));
  if (blockIdx.x == 0 && threadIdx.x == 0) out[BATCH] = (float)t;
}

// ---------------------------------------------------------------------------
extern "C" void kernel_launch(void* const* d_in, const int* in_sizes, int n_in,
                              void* d_out, int out_size, void* d_ws, size_t ws_size,
                              hipStream_t stream)
{
  (void)in_sizes; (void)n_in; (void)out_size; (void)ws_size;
  const float* embP  = (const float*)d_in[0];
  const float* embR  = (const float*)d_in[1];
  const float* encW1 = (const float*)d_in[2];
  const float* encB1 = (const float*)d_in[3];
  const float* ln1g  = (const float*)d_in[4];
  const float* ln1b  = (const float*)d_in[5];
  const float* encW2 = (const float*)d_in[6];
  const float* encB2 = (const float*)d_in[7];
  const float* ln2g  = (const float*)d_in[8];
  const float* ln2b  = (const float*)d_in[9];
  const float* gW1   = (const float*)d_in[10];
  const float* gb1   = (const float*)d_in[11];
  const float* gW2   = (const float*)d_in[12];
  const float* gb2   = (const float*)d_in[13];
  const float* We1   = (const float*)d_in[14];
  const float* be1   = (const float*)d_in[15];
  const float* We2   = (const float*)d_in[16];
  const float* be2   = (const float*)d_in[17];
  const float* tW1   = (const float*)d_in[18];
  const float* tb1   = (const float*)d_in[19];
  const float* tW2   = (const float*)d_in[20];
  const float* tb2   = (const float*)d_in[21];
  const float* tW3   = (const float*)d_in[22];
  const float* tb3   = (const float*)d_in[23];
  const int* taskPtr = (const int*)d_in[24];

  float* out = (float*)d_out;
  char* ws = (char*)d_ws;
  const size_t MB = 1ull << 20;

  // Lifetime-aliased workspace (peak ~209 MB):
  //  [0,64):    x0[0,32),x1[32,64) -> feat fp32[0,64) -> e1b[0,48) ->
  //             mix16[0,16), t1f16[16,24), t2f16[24,28)
  //  [64,192):  h0[64,128),h1[128,192) -> We1t0[64,80),We2t0[80,88),
  //             feat16[88,120),eob[120,168)
  //  [192,208): W1t0/W1t1 [192,200) -> gbuf[192,200) -> tW1t[192,193),tW2t[193,..)
  //             | W2t0/W2t1 [200,208)
  //  [208,~209): metadata
  unsigned short* x0   = (unsigned short*)(ws);
  unsigned short* x1   = (unsigned short*)(ws + 32 * MB);
  float* feat = (float*)(ws);
  unsigned short* e1b  = (unsigned short*)(ws);
  unsigned short* mix16 = (unsigned short*)(ws);
  unsigned short* t1f16 = (unsigned short*)(ws + 16 * MB);
  unsigned short* t2f16 = (unsigned short*)(ws + 24 * MB);
  unsigned short* h0    = (unsigned short*)(ws + 64 * MB);
  unsigned short* h1    = (unsigned short*)(ws + 128 * MB);
  unsigned short* We1t0 = (unsigned short*)(ws + 64 * MB);
  unsigned short* We2t0 = (unsigned short*)(ws + 80 * MB);
  unsigned short* feat16= (unsigned short*)(ws + 88 * MB);
  unsigned short* eob   = (unsigned short*)(ws + 120 * MB);
  unsigned short* W1t0  = (unsigned short*)(ws + 192 * MB);
  unsigned short* W1t1  = (unsigned short*)(ws + 196 * MB);
  unsigned short* W2t0  = (unsigned short*)(ws + 200 * MB);
  unsigned short* W2t1  = (unsigned short*)(ws + 204 * MB);
  float* gbuf = (float*)(ws + 192 * MB);
  unsigned short* tW1t = (unsigned short*)(ws + 192 * MB);
  unsigned short* tW2t = (unsigned short*)(ws + 193 * MB);
  char* small = ws + 208 * MB;
  int*   counts    = (int*)  (small);
  int*   offs      = (int*)  (small + 1024);
  int*   chunkCnt  = (int*)  (small + 2048);
  int*   chunkBase = (int*)  (small + 2048 + 4096);
  int*   topkIdx   = (int*)  (small + 16384);
  float* topkW     = (float*)(small + 16384 + 196608);
  int*   pairRow   = (int*)  (small + 16384 + 2 * 196608);
  float* pairW     = (float*)(small + 16384 + 3 * 196608);
  int*   rowPos    = (int*)  (small + 16384 + 4 * 196608);

  const dim3 blk(256, 1, 1);

  // input conversion + encoder GEMM1: h = concat @ W1 + b1 (fp16 split, 3 terms)
  convx_k<<<dim3(16384, 1, 1), blk, 0, stream>>>(embP, embR, x0, x1);
  transp_k<2,0><<<dim3(DIN/32, DHID/32, 1), blk, 0, stream>>>(encW1, W1t0, W1t1, nullptr, DIN, DHID);
  mgemm_k<1,0,0,32,DHID/128,0><<<dim3((BATCH/128)*(DHID/128), 1, 1), blk, 0, stream>>>(
      x0, x1, W1t0, W1t1, encB1, nullptr, h0, h1,
      nullptr, nullptr, nullptr, nullptr, nullptr, BATCH, DHID, DIN);
  ln_pair_k<DHID, true><<<dim3(BATCH, 1, 1), blk, 0, stream>>>(h0, h1, ln1g, ln1b);

  // encoder GEMM2: feat = h @ W2 + b2 (fp16 split, 3 terms) -> fp32
  transp_k<2,0><<<dim3(DHID/32, DIN/32, 1), blk, 0, stream>>>(encW2, W2t0, W2t1, nullptr, DHID, DIN);
  mgemm_k<1,0,3,32,DIN/128,0><<<dim3((BATCH/128)*(DIN/128), 1, 1), blk, 0, stream>>>(
      h0, h1, W2t0, W2t1, encB2, feat, nullptr, nullptr,
      nullptr, nullptr, nullptr, nullptr, nullptr, BATCH, DIN, DHID);
  // feat LN: fp32 in-place + fused fp16 mirror for the expert path
  ln_k<DIN, false, true><<<dim3(BATCH, 1, 1), blk, 0, stream>>>(feat, ln2g, ln2b, feat16);

  // gate (fp32 vector path on fp32 feat) — no global atomics anywhere
  gemm32_k<true><<<dim3(BATCH/128, 1, 1), blk, 0, stream>>>(
      feat, gW1, gb1, gbuf, taskPtr, BATCH, 128, DIN);
  gate_topk_k<<<dim3(BATCH/4, 1, 1), blk, 0, stream>>>(
      gbuf, gW2, gb2, taskPtr, out + BATCH + 1, topkIdx, topkW);
  hist_k<<<dim3(BATCH/256, 1, 1), blk, 0, stream>>>(topkIdx, chunkCnt);
  scanB_k<<<dim3(1, 1, 1), dim3(64, 1, 1), 0, stream>>>(chunkCnt, counts, offs, chunkBase);
  fill2_k<<<dim3(BATCH/256, 1, 1), blk, 0, stream>>>(topkIdx, topkW, chunkBase,
                                                     pairRow, pairW, rowPos);

  // expert weights in fp16 (h region free now)
  transp_k<1,0><<<dim3(DIN/32, EXPSZ/32, NEXP), blk, 0, stream>>>(We1, We1t0, nullptr, nullptr, DIN, EXPSZ);
  transp_k<1,0><<<dim3(EXPSZ/32, EXPSZ/32, NEXP), blk, 0, stream>>>(We2, We2t0, nullptr, nullptr, EXPSZ, EXPSZ);

  // expert GEMM1: e1 = relu(feat16[pairRow] @ We1[e] + be1)  (plain fp16)
  mgemm_k<0,1,1,64,EXPSZ/128,0><<<dim3((BATCH/128)*(EXPSZ/128), 1, NEXP), blk, 0, stream>>>(
      feat16, nullptr, We1t0, nullptr, be1, nullptr, e1b, nullptr,
      pairRow, nullptr, counts, offs, nullptr, NPAIR, EXPSZ, DIN);
  // expert GEMM2: eo = w_p * (e1 @ We2[e] + be2)  (plain fp16)
  mgemm_k<0,2,2,64,EXPSZ/128,0><<<dim3((BATCH/128)*(EXPSZ/128), 1, NEXP), blk, 0, stream>>>(
      e1b, nullptr, We2t0, nullptr, be2, nullptr, eob, nullptr,
      nullptr, pairW, counts, offs, nullptr, NPAIR, EXPSZ, EXPSZ);
  mixreduce_k<<<dim3(BATCH, 1, 1), blk, 0, stream>>>(eob, rowPos, mix16);

  // towers (plain fp16 MFMA, task-indexed weights/bias)
  transp_k<1,1><<<dim3(EXPSZ/32, 256/32, 1), blk, 0, stream>>>(tW1, tW1t, nullptr, taskPtr, EXPSZ, 256);
  transp_k<1,1><<<dim3(256/32, 128/32, 1), blk, 0, stream>>>(tW2, tW2t, nullptr, taskPtr, 256, 128);
  mgemm_k<0,0,1,64,2,1><<<dim3((BATCH/128)*2, 1, 1), blk, 0, stream>>>(
      mix16, nullptr, tW1t, nullptr, tb1, nullptr, t1f16, nullptr,
      nullptr, nullptr, nullptr, nullptr, taskPtr, BATCH, 256, EXPSZ);
  mgemm_k<0,0,1,64,1,1><<<dim3(BATCH/128, 1, 1), blk, 0, stream>>>(
      t1f16, nullptr, tW2t, nullptr, tb2, nullptr, t2f16, nullptr,
      nullptr, nullptr, nullptr, nullptr, taskPtr, BATCH, 128, 256);
  tower3_k<<<dim3(BATCH/4, 1, 1), blk, 0, stream>>>(t2f16, tW3, tb3, taskPtr, out);
}

// Round 12
// 1218.286 us; speedup vs baseline: 1.4890x; 1.4890x over previous
//
#include <hip/hip_runtime.h>

typedef __attribute__((ext_vector_type(8))) _Float16 f16x8;
typedef __attribute__((ext_vector_type(4))) float f32x4;

#define DEVINL __device__ __forceinline__

constexpr int BATCH = 16384;
constexpr int DIN   = 1024;
constexpr int DHID  = 2048;
constexpr int NEXP  = 16;
constexpr int EXPSZ = 512;
constexpr int NPAIR = BATCH * 3;

DEVINL unsigned short f2h(float v) {
  _Float16 h = (_Float16)v;
  return __builtin_bit_cast(unsigned short, h);
}
DEVINL float h2f(unsigned short u) {
  return (float)__builtin_bit_cast(_Float16, u);
}

DEVINL void gl2lds(const unsigned short* src, char* ldst) {
  __builtin_amdgcn_global_load_lds((const __attribute__((address_space(1))) void*)src,
                                   (__attribute__((address_space(3))) void*)ldst, 16, 0, 0);
}

// ---------------------------------------------------------------------------
// fp16 split-MFMA GEMM, 128x128 tile, 4 waves (2x2 of 64x64), 16x16x32 f16.
// Operands staged via global_load_lds (fragment-contiguous LDS). 1D grid
// (x = NXT*NYT tiles, z = expert); row-tiles round-robined across XCDs,
// col-tiles consecutive within an XCD (load-balanced under early-exit +
// A-panel L2 reuse; bijective for NXT%8==0 — speed-only).
// OCCUPANCY NOTE (r11 lesson): SPLIT kernels MUST stay at 2 blocks/CU.
// At 3 blocks/CU the L2 working set (staging panels + partially-filled
// epilogue write lines) overflows the 4MB/XCD L2: WRITE_SIZE 208MB->1GB,
// MfmaUtil 25%->13%, 2x slower. Occupancy is not monotonic here.
// SPLIT=1: v = c0 + c1/2048 (c1 stored x2048). 3 MFMA terms. SPLIT=0: fp16.
// AMODE: 0 linear A rows; 1 gather via pairRow; 2 pair-linear.
// TASK:  bias += (*taskPtr)*N (task-indexed tower bias; B pre-extracted).
// EPI:   0 +bias -> fp16 hi/lo pair; 1 +bias,relu -> fp16;
//        2 +bias,*pairW -> fp16; 3 +bias -> fp32.
// ---------------------------------------------------------------------------
template<int SPLIT, int AMODE, int EPI, int BK, int NYT, int TASK>
__global__ __launch_bounds__(256, SPLIT ? 2 : 3)
void mgemm_k(const unsigned short* __restrict__ A0p,
             const unsigned short* __restrict__ A1p,
             const unsigned short* __restrict__ B0p,
             const unsigned short* __restrict__ B1p,
             const float* __restrict__ biasb,
             float* __restrict__ Cf, unsigned short* __restrict__ Cb0,
             unsigned short* __restrict__ Cb1,
             const int* __restrict__ pairRow, const float* __restrict__ pairW,
             const int* __restrict__ counts, const int* __restrict__ offs,
             const int* __restrict__ taskPtr,
             int M, int N, int K)
{
  constexpr int KG = BK / 8;
  constexpr int UNITS = 128 * KG;
  constexpr int ISS = UNITS / 256;
  constexpr int NKK = BK / 32;
  constexpr int NARR = SPLIT ? 4 : 2;
  constexpr bool EXPERT = (AMODE == 1 || AMODE == 2);
  __shared__ char smem[NARR * UNITS * 16];
  char* sA0 = smem;
  char* sA1 = smem + UNITS * 16;                    // iff SPLIT
  char* sB0 = smem + (SPLIT ? 2 : 1) * UNITS * 16;
  char* sB1 = smem + 3 * UNITS * 16;                // iff SPLIT

  int Mloc = M, rowBase = 0;
  const unsigned short* b0 = B0p;
  const unsigned short* b1 = B1p;
  const float* bias = biasb;
  if (EXPERT) {
    const int e = blockIdx.z;
    Mloc = counts[e];
    rowBase = offs[e];
    const size_t eo = (size_t)e * (size_t)K * N;
    b0 = B0p + eo;
    if (SPLIT) b1 = B1p + eo;
    bias = biasb + (size_t)e * N;
  }
  if (TASK) bias = biasb + (size_t)(*taskPtr) * N;

  // round-robin row-tiles over XCDs; col-tiles consecutive within XCD
  const int xcd = (int)blockIdx.x & 7;
  const int j   = (int)blockIdx.x >> 3;
  const int tile0 = (xcd + 8 * (j / NYT)) * 128;
  const int col0  = (j % NYT) * 128;
  if (tile0 >= Mloc) return;

  const int tid = threadIdx.x;
  const int lane = tid & 63;
  const int wr = ((tid >> 6) >> 1) * 64;
  const int wc = ((tid >> 6) & 1) * 64;
  const int l15 = lane & 15;
  const int lg = lane >> 4;

  // per-thread staging row (fixed across K)
  const int srow = tid & 127;
  size_t aoff;
  if (AMODE == 0) {
    aoff = (size_t)(tile0 + srow) * K;
  } else if (AMODE == 1) {
    int p = rowBase + tile0 + srow; p = p < NPAIR - 1 ? p : NPAIR - 1;
    aoff = (size_t)pairRow[p] * K;
  } else {
    int p = rowBase + tile0 + srow; p = p < NPAIR - 1 ? p : NPAIR - 1;
    aoff = (size_t)p * K;
  }
  const size_t boff = (size_t)(col0 + srow) * K;

  f32x4 acc[4][4];
  f32x4 acc2[4][4];
  #pragma unroll
  for (int m = 0; m < 4; ++m)
    #pragma unroll
    for (int n = 0; n < 4; ++n) {
      acc[m][n] = f32x4{0.f, 0.f, 0.f, 0.f};
      if (SPLIT) acc2[m][n] = f32x4{0.f, 0.f, 0.f, 0.f};
    }

  for (int kt = 0; kt < K; kt += BK) {
    #pragma unroll
    for (int it = 0; it < ISS; ++it) {
      const int uo = (it * 256 + (tid & 192)) * 16;   // wave-uniform LDS base
      const int ko = kt + (it * 2 + (tid >> 7)) * 8;
      gl2lds(A0p + aoff + ko, sA0 + uo);
      if (SPLIT) gl2lds(A1p + aoff + ko, sA1 + uo);
      gl2lds(b0 + boff + ko, sB0 + uo);
      if (SPLIT) gl2lds(b1 + boff + ko, sB1 + uo);
    }
    __syncthreads();
    #pragma unroll
    for (int kk = 0; kk < NKK; ++kk) {
      const int g = kk * 4 + lg;
      f16x8 b0f[4], b1f[4];
      #pragma unroll
      for (int n = 0; n < 4; ++n) {
        const size_t off = (size_t)(g * 128 + wc + n * 16 + l15) * 16;
        b0f[n] = *(const f16x8*)(sB0 + off);
        if (SPLIT) b1f[n] = *(const f16x8*)(sB1 + off);
      }
      #pragma unroll
      for (int m = 0; m < 4; ++m) {
        const size_t ao = (size_t)(g * 128 + wr + m * 16 + l15) * 16;
        const f16x8 a0 = *(const f16x8*)(sA0 + ao);
        f16x8 a1;
        if (SPLIT) a1 = *(const f16x8*)(sA1 + ao);
        #pragma unroll
        for (int n = 0; n < 4; ++n) {
          if (SPLIT) {
            acc2[m][n] = __builtin_amdgcn_mfma_f32_16x16x32_f16(a1, b0f[n], acc2[m][n], 0, 0, 0);
            acc2[m][n] = __builtin_amdgcn_mfma_f32_16x16x32_f16(a0, b1f[n], acc2[m][n], 0, 0, 0);
          }
          acc[m][n] = __builtin_amdgcn_mfma_f32_16x16x32_f16(a0, b0f[n], acc[m][n], 0, 0, 0);
        }
      }
    }
    __syncthreads();
  }

  // epilogue. C/D mapping: col = lane&15, row = (lane>>4)*4 + j  [m89-verified]
  #pragma unroll
  for (int n = 0; n < 4; ++n) {
    const int cn = col0 + wc + n * 16 + l15;
    const float bv = bias[cn];
    #pragma unroll
    for (int m = 0; m < 4; ++m) {
      const int r0 = wr + m * 16 + ((lane >> 4) << 2);
      #pragma unroll
      for (int jj = 0; jj < 4; ++jj) {
        const int rm = tile0 + r0 + jj;
        if (EXPERT && rm >= Mloc) continue;
        float v = acc[m][n][jj];
        if (SPLIT) v += acc2[m][n][jj] * (1.f / 2048.f);
        v += bv;
        const size_t ci = (size_t)(EXPERT ? (rowBase + rm) : rm) * N + cn;
        if (EPI == 0) {
          const unsigned short h0 = f2h(v);
          Cb0[ci] = h0;
          Cb1[ci] = f2h((v - h2f(h0)) * 2048.f);
        } else if (EPI == 1) {
          Cb0[ci] = f2h(fmaxf(v, 0.f));
        } else if (EPI == 2) {
          Cb0[ci] = f2h(v * pairW[rowBase + rm]);
        } else {
          Cf[ci] = v;
        }
      }
    }
  }
}

// ---------------------------------------------------------------------------
// fp32 vector GEMM (gate). C = relu(A@B[t] + bias[t]), fp32.
// ---------------------------------------------------------------------------
template<bool RELU>
__global__ __launch_bounds__(256, 2)
void gemm32_k(const float* __restrict__ Av, const float* __restrict__ Bb,
              const float* __restrict__ biasb, float* __restrict__ Cv,
              const int* __restrict__ taskPtr, int M, int N, int K)
{
  __shared__ float As[16][128];
  __shared__ float Bs[16][128];
  const int t = *taskPtr;
  const float* Bw = Bb + (size_t)t * K * N;
  const float* bias = biasb + (size_t)t * N;
  const int tile0 = blockIdx.x * 128;
  const int col0 = blockIdx.y * 128;
  const int tid = threadIdx.x;
  const int am = tid >> 1, ak = (tid & 1) * 8;
  const int bk = tid >> 4, bn = (tid & 15) * 8;
  const int rg = (tid >> 4) * 8, cg = (tid & 15) * 8;
  const float* aptr = Av + (size_t)(tile0 + am) * K;

  float acc[8][8];
  #pragma unroll
  for (int i = 0; i < 8; ++i)
    #pragma unroll
    for (int j = 0; j < 8; ++j) acc[i][j] = 0.f;

  for (int kt = 0; kt < K; kt += 16) {
    {
      const float* src = aptr + kt + ak;
      float4 x0 = *reinterpret_cast<const float4*>(src);
      float4 x1 = *reinterpret_cast<const float4*>(src + 4);
      As[ak+0][am]=x0.x; As[ak+1][am]=x0.y; As[ak+2][am]=x0.z; As[ak+3][am]=x0.w;
      As[ak+4][am]=x1.x; As[ak+5][am]=x1.y; As[ak+6][am]=x1.z; As[ak+7][am]=x1.w;
    }
    {
      const float* bsrc = Bw + (size_t)(kt + bk) * N + (col0 + bn);
      float4 b0 = *reinterpret_cast<const float4*>(bsrc);
      float4 b1 = *reinterpret_cast<const float4*>(bsrc + 4);
      Bs[bk][bn+0]=b0.x; Bs[bk][bn+1]=b0.y; Bs[bk][bn+2]=b0.z; Bs[bk][bn+3]=b0.w;
      Bs[bk][bn+4]=b1.x; Bs[bk][bn+5]=b1.y; Bs[bk][bn+6]=b1.z; Bs[bk][bn+7]=b1.w;
    }
    __syncthreads();
    #pragma unroll
    for (int k = 0; k < 16; ++k) {
      float4 a0 = *reinterpret_cast<const float4*>(&As[k][rg]);
      float4 a1 = *reinterpret_cast<const float4*>(&As[k][rg + 4]);
      float4 c0 = *reinterpret_cast<const float4*>(&Bs[k][cg]);
      float4 c1 = *reinterpret_cast<const float4*>(&Bs[k][cg + 4]);
      const float a[8] = {a0.x,a0.y,a0.z,a0.w,a1.x,a1.y,a1.z,a1.w};
      const float b[8] = {c0.x,c0.y,c0.z,c0.w,c1.x,c1.y,c1.z,c1.w};
      #pragma unroll
      for (int i = 0; i < 8; ++i)
        #pragma unroll
        for (int j = 0; j < 8; ++j)
          acc[i][j] = fmaf(a[i], b[j], acc[i][j]);
    }
    __syncthreads();
  }
  #pragma unroll
  for (int i = 0; i < 8; ++i) {
    const int mr = tile0 + rg + i;
    #pragma unroll
    for (int j = 0; j < 8; ++j) {
      float v = acc[i][j] + bias[col0 + cg + j];
      if (RELU) v = fmaxf(v, 0.f);
      Cv[(size_t)mr * N + col0 + cg + j] = v;
    }
  }
}

// ---------------------------------------------------------------------------
// transpose+convert: src fp32 [z][R][C] -> fp16 level arrays [z][C][R].
// LEV=2: level-1 stored x2048. TASK: src += (*taskPtr)*R*C (extract task t).
// ---------------------------------------------------------------------------
template<int LEV, int TASK>
__global__ __launch_bounds__(256)
void transp_k(const float* __restrict__ src, unsigned short* __restrict__ d0,
              unsigned short* __restrict__ d1, const int* __restrict__ taskPtr,
              int R, int C)
{
  __shared__ float tle[32][33];
  size_t bb = (size_t)blockIdx.z * R * C;
  if (TASK) bb = (size_t)(*taskPtr) * R * C;
  const int r0 = blockIdx.x * 32, c0 = blockIdx.y * 32;
  const int x = threadIdx.x & 31, y = threadIdx.x >> 5;
  #pragma unroll
  for (int i = 0; i < 32; i += 8)
    tle[y + i][x] = src[bb + (size_t)(r0 + y + i) * C + (c0 + x)];
  __syncthreads();
  const size_t db = TASK ? 0 : (size_t)blockIdx.z * R * C;
  #pragma unroll
  for (int i = 0; i < 32; i += 8) {
    const float v = tle[x][y + i];
    const size_t di = db + (size_t)(c0 + y + i) * R + (r0 + x);
    const unsigned short h0 = f2h(v);
    d0[di] = h0;
    if (LEV > 1) d1[di] = f2h((v - h2f(h0)) * 2048.f);
  }
}

// concat(embP,embR) fp32 -> fp16 hi/lo pair arrays [B][1024]
__global__ __launch_bounds__(256)
void convx_k(const float* __restrict__ eP, const float* __restrict__ eR,
             unsigned short* __restrict__ x0, unsigned short* __restrict__ x1)
{
  const size_t u = (size_t)blockIdx.x * 256 + threadIdx.x;  // 4-elem units
  const size_t row = u >> 8;
  const int c4 = (int)(u & 255) * 4;
  const float* s = (c4 < 512) ? (eP + row * 512 + c4) : (eR + row * 512 + (c4 - 512));
  const float4 v = *(const float4*)s;
  const float vv[4] = {v.x, v.y, v.z, v.w};
  ushort4 h4, l4;
  unsigned short* hp = (unsigned short*)&h4;
  unsigned short* lp = (unsigned short*)&l4;
  #pragma unroll
  for (int j = 0; j < 4; ++j) {
    const unsigned short h0 = f2h(vv[j]);
    hp[j] = h0;
    lp[j] = f2h((vv[j] - h2f(h0)) * 2048.f);
  }
  *(ushort4*)(x0 + row * 1024 + c4) = h4;
  *(ushort4*)(x1 + row * 1024 + c4) = l4;
}

// ---------------------------------------------------------------------------
// In-place LayerNorm + relu over fp16 hi/lo pair rows (fp32 math).
// ---------------------------------------------------------------------------
template<int COLS, bool RELU>
__global__ __launch_bounds__(256)
void ln_pair_k(unsigned short* __restrict__ h0, unsigned short* __restrict__ h1,
               const float* __restrict__ g, const float* __restrict__ b)
{
  constexpr int PER = COLS / 256;
  const size_t row = blockIdx.x;
  unsigned short* r0 = h0 + row * COLS;
  unsigned short* r1 = h1 + row * COLS;
  const int c0 = threadIdx.x * PER;
  float v[PER];
  float s = 0.f, s2 = 0.f;
  #pragma unroll
  for (int i = 0; i < PER; i += 4) {
    const ushort4 a = *(const ushort4*)(r0 + c0 + i);
    const ushort4 c = *(const ushort4*)(r1 + c0 + i);
    v[i+0] = h2f(a.x) + h2f(c.x) * (1.f/2048.f);
    v[i+1] = h2f(a.y) + h2f(c.y) * (1.f/2048.f);
    v[i+2] = h2f(a.z) + h2f(c.z) * (1.f/2048.f);
    v[i+3] = h2f(a.w) + h2f(c.w) * (1.f/2048.f);
  }
  #pragma unroll
  for (int i = 0; i < PER; ++i) { s += v[i]; s2 += v[i] * v[i]; }
  #pragma unroll
  for (int o = 1; o < 64; o <<= 1) { s += __shfl_xor(s, o); s2 += __shfl_xor(s2, o); }
  __shared__ float ss[4], ss2[4];
  const int w = threadIdx.x >> 6;
  if ((threadIdx.x & 63) == 0) { ss[w] = s; ss2[w] = s2; }
  __syncthreads();
  s  = ss[0] + ss[1] + ss[2] + ss[3];
  s2 = ss2[0] + ss2[1] + ss2[2] + ss2[3];
  const float mu = s * (1.f / COLS);
  const float var = s2 * (1.f / COLS) - mu * mu;
  const float rs = rsqrtf(var + 1e-5f);
  #pragma unroll
  for (int i = 0; i < PER; i += 4) {
    ushort4 a4, c4v;
    unsigned short* ap = (unsigned short*)&a4;
    unsigned short* cp = (unsigned short*)&c4v;
    #pragma unroll
    for (int j = 0; j < 4; ++j) {
      const int c = c0 + i + j;
      float y = (v[i+j] - mu) * rs * g[c] + b[c];
      if (RELU) y = fmaxf(y, 0.f);
      const unsigned short hh = f2h(y);
      ap[j] = hh;
      cp[j] = f2h((y - h2f(hh)) * 2048.f);
    }
    *(ushort4*)(r0 + c0 + i) = a4;
    *(ushort4*)(r1 + c0 + i) = c4v;
  }
}

// ---------------------------------------------------------------------------
// In-place LayerNorm over fp32 rows; optionally also emit fp16 mirror.
// ---------------------------------------------------------------------------
template<int COLS, bool RELU, bool F16OUT>
__global__ __launch_bounds__(256)
void ln_k(float* __restrict__ x, const float* __restrict__ g, const float* __restrict__ b,
          unsigned short* __restrict__ x16)
{
  constexpr int PER = COLS / 256;
  const size_t row = blockIdx.x;
  float* xr = x + row * COLS;
  float v[PER];
  float s = 0.f, s2 = 0.f;
  #pragma unroll
  for (int i = 0; i < PER; ++i) {
    v[i] = xr[threadIdx.x + i * 256];
    s += v[i];
    s2 += v[i] * v[i];
  }
  #pragma unroll
  for (int o = 1; o < 64; o <<= 1) { s += __shfl_xor(s, o); s2 += __shfl_xor(s2, o); }
  __shared__ float ss[4], ss2[4];
  const int w = threadIdx.x >> 6;
  if ((threadIdx.x & 63) == 0) { ss[w] = s; ss2[w] = s2; }
  __syncthreads();
  s  = ss[0] + ss[1] + ss[2] + ss[3];
  s2 = ss2[0] + ss2[1] + ss2[2] + ss2[3];
  const float mu = s * (1.f / COLS);
  const float var = s2 * (1.f / COLS) - mu * mu;
  const float rs = rsqrtf(var + 1e-5f);
  #pragma unroll
  for (int i = 0; i < PER; ++i) {
    const int c = threadIdx.x + i * 256;
    float y = (v[i] - mu) * rs * g[c] + b[c];
    if (RELU) y = fmaxf(y, 0.f);
    xr[c] = y;
    if (F16OUT) x16[row * COLS + c] = f2h(y);
  }
}

// ---------------------------------------------------------------------------
// gate: logits = relu-g @ gW2[t] + gb2[t]; top-3 softmax; NO global atomics.
// ---------------------------------------------------------------------------
__global__ __launch_bounds__(256)
void gate_topk_k(const float* __restrict__ g, const float* __restrict__ gW2,
                 const float* __restrict__ gb2, const int* __restrict__ taskPtr,
                 float* __restrict__ gatesOut, int* __restrict__ topkIdx,
                 float* __restrict__ topkW)
{
  const int t = *taskPtr;
  const float* W = gW2 + (size_t)t * 128 * 16;
  const float* bias = gb2 + (size_t)t * 16;
  const int lane = threadIdx.x & 63;
  const int row = blockIdx.x * 4 + (threadIdx.x >> 6);
  const float* gr = g + (size_t)row * 128;
  const int e = lane & 15;
  const int q = lane >> 4;
  float s = 0.f;
  for (int j = q * 32; j < q * 32 + 32; ++j) s = fmaf(gr[j], W[j * 16 + e], s);
  s += __shfl_xor(s, 16);
  s += __shfl_xor(s, 32);
  s += bias[e];
  float logits[16];
  #pragma unroll
  for (int i = 0; i < 16; ++i) logits[i] = __shfl(s, i);
  int i0 = 0; float v0 = logits[0];
  #pragma unroll
  for (int i = 1; i < 16; ++i) if (logits[i] > v0) { v0 = logits[i]; i0 = i; }
  int i1 = -1; float v1 = -3.4e38f;
  #pragma unroll
  for (int i = 0; i < 16; ++i) if (i != i0 && logits[i] > v1) { v1 = logits[i]; i1 = i; }
  int i2 = -1; float v2 = -3.4e38f;
  #pragma unroll
  for (int i = 0; i < 16; ++i) if (i != i0 && i != i1 && logits[i] > v2) { v2 = logits[i]; i2 = i; }
  const float ex1 = expf(v1 - v0);
  const float ex2 = expf(v2 - v0);
  const float inv = 1.f / (1.f + ex1 + ex2);
  const float p0 = inv, p1 = ex1 * inv, p2 = ex2 * inv;
  if (lane < 16) {
    const float gv = (lane == i0) ? p0 : (lane == i1) ? p1 : (lane == i2) ? p2 : 0.f;
    gatesOut[(size_t)row * 16 + lane] = gv;
  }
  if (lane == 0) {
    topkIdx[row * 3 + 0] = i0; topkIdx[row * 3 + 1] = i1; topkIdx[row * 3 + 2] = i2;
    topkW [row * 3 + 0] = p0; topkW [row * 3 + 1] = p1; topkW [row * 3 + 2] = p2;
  }
}

// per-chunk expert histogram (LDS atomics only)
__global__ __launch_bounds__(256)
void hist_k(const int* __restrict__ topkIdx, int* __restrict__ chunkCnt)
{
  __shared__ int lc[NEXP];
  if (threadIdx.x < NEXP) lc[threadIdx.x] = 0;
  __syncthreads();
  const int row = blockIdx.x * 256 + threadIdx.x;
  #pragma unroll
  for (int k = 0; k < 3; ++k) atomicAdd(&lc[topkIdx[row * 3 + k]], 1);
  __syncthreads();
  if (threadIdx.x < NEXP) chunkCnt[blockIdx.x * NEXP + threadIdx.x] = lc[threadIdx.x];
}

// serial scan: counts/offs per expert + per-chunk bases
__global__ void scanB_k(const int* __restrict__ chunkCnt, int* __restrict__ counts,
                        int* __restrict__ offs, int* __restrict__ chunkBase)
{
  if (threadIdx.x == 0) {
    int tot[NEXP];
    for (int e = 0; e < NEXP; ++e) tot[e] = 0;
    for (int c = 0; c < 64; ++c)
      for (int e = 0; e < NEXP; ++e) tot[e] += chunkCnt[c * NEXP + e];
    int a = 0;
    for (int e = 0; e < NEXP; ++e) { offs[e] = a; counts[e] = tot[e]; a += tot[e]; }
    for (int e = 0; e < NEXP; ++e) {
      int b = offs[e];
      for (int c = 0; c < 64; ++c) { chunkBase[c * NEXP + e] = b; b += chunkCnt[c * NEXP + e]; }
    }
  }
}

// fill pair lists: LDS-atomic within-chunk offsets + precomputed chunk base
__global__ __launch_bounds__(256)
void fill2_k(const int* __restrict__ topkIdx, const float* __restrict__ topkW,
             const int* __restrict__ chunkBase, int* __restrict__ pairRow,
             float* __restrict__ pairW, int* __restrict__ rowPos)
{
  __shared__ int lc[NEXP];
  if (threadIdx.x < NEXP) lc[threadIdx.x] = 0;
  __syncthreads();
  const int row = blockIdx.x * 256 + threadIdx.x;
  #pragma unroll
  for (int k = 0; k < 3; ++k) {
    const int e = topkIdx[row * 3 + k];
    const int lofs = atomicAdd(&lc[e], 1);
    const int pos = chunkBase[blockIdx.x * NEXP + e] + lofs;
    pairRow[pos] = row;
    pairW[pos] = topkW[row * 3 + k];
    rowPos[row * 3 + k] = pos;
  }
}

// mix (fp16 out) = sum of the row's 3 eo slots
__global__ __launch_bounds__(256)
void mixreduce_k(const unsigned short* __restrict__ eo, const int* __restrict__ rowPos,
                 unsigned short* __restrict__ mix16)
{
  const size_t row = blockIdx.x;
  const size_t p0 = rowPos[row * 3 + 0];
  const size_t p1 = rowPos[row * 3 + 1];
  const size_t p2 = rowPos[row * 3 + 2];
  for (int c = threadIdx.x; c < EXPSZ; c += 256) {
    mix16[row * EXPSZ + c] = f2h(h2f(eo[p0 * EXPSZ + c]) + h2f(eo[p1 * EXPSZ + c])
                               + h2f(eo[p2 * EXPSZ + c]));
  }
}

__global__ __launch_bounds__(256)
void tower3_k(const unsigned short* __restrict__ t2, const float* __restrict__ tW3,
              const float* __restrict__ tb3, const int* __restrict__ taskPtr,
              float* __restrict__ out)
{
  const int t = *taskPtr;
  const float* w = tW3 + (size_t)t * 128;
  const float bias = tb3[t];
  const int lane = threadIdx.x & 63;
  const int row = blockIdx.x * 4 + (threadIdx.x >> 6);
  const unsigned short* x = t2 + (size_t)row * 128;
  float s = fmaf(h2f(x[lane]), w[lane], h2f(x[lane + 64]) * w[lane + 64]);
  #pragma unroll
  for (int o = 1; o < 64; o <<= 1) s += __shfl_xor(s, o);
  if (lane == 0) out[row] = 1.f / (1.f + expf(-(s + bias)));
  if (blockIdx.x == 0 && threadIdx.x == 0) out[BATCH] = (float)t;
}

// ---------------------------------------------------------------------------
extern "C" void kernel_launch(void* const* d_in, const int* in_sizes, int n_in,
                              void* d_out, int out_size, void* d_ws, size_t ws_size,
                              hipStream_t stream)
{
  (void)in_sizes; (void)n_in; (void)out_size; (void)ws_size;
  const float* embP  = (const float*)d_in[0];
  const float* embR  = (const float*)d_in[1];
  const float* encW1 = (const float*)d_in[2];
  const float* encB1 = (const float*)d_in[3];
  const float* ln1g  = (const float*)d_in[4];
  const float* ln1b  = (const float*)d_in[5];
  const float* encW2 = (const float*)d_in[6];
  const float* encB2 = (const float*)d_in[7];
  const float* ln2g  = (const float*)d_in[8];
  const float* ln2b  = (const float*)d_in[9];
  const float* gW1   = (const float*)d_in[10];
  const float* gb1   = (const float*)d_in[11];
  const float* gW2   = (const float*)d_in[12];
  const float* gb2   = (const float*)d_in[13];
  const float* We1   = (const float*)d_in[14];
  const float* be1   = (const float*)d_in[15];
  const float* We2   = (const float*)d_in[16];
  const float* be2   = (const float*)d_in[17];
  const float* tW1   = (const float*)d_in[18];
  const float* tb1   = (const float*)d_in[19];
  const float* tW2   = (const float*)d_in[20];
  const float* tb2   = (const float*)d_in[21];
  const float* tW3   = (const float*)d_in[22];
  const float* tb3   = (const float*)d_in[23];
  const int* taskPtr = (const int*)d_in[24];

  float* out = (float*)d_out;
  char* ws = (char*)d_ws;
  const size_t MB = 1ull << 20;

  // Lifetime-aliased workspace (peak ~209 MB):
  //  [0,64):    x0[0,32),x1[32,64) -> feat fp32[0,64) -> e1b[0,48) ->
  //             mix16[0,16), t1f16[16,24), t2f16[24,28)
  //  [64,192):  h0[64,128),h1[128,192) -> We1t0[64,80),We2t0[80,88),
  //             feat16[88,120),eob[120,168)
  //  [192,208): W1t0/W1t1 [192,200) -> gbuf[192,200) -> tW1t[192,193),tW2t[193,..)
  //             | W2t0/W2t1 [200,208)
  //  [208,~209): metadata
  unsigned short* x0   = (unsigned short*)(ws);
  unsigned short* x1   = (unsigned short*)(ws + 32 * MB);
  float* feat = (float*)(ws);
  unsigned short* e1b  = (unsigned short*)(ws);
  unsigned short* mix16 = (unsigned short*)(ws);
  unsigned short* t1f16 = (unsigned short*)(ws + 16 * MB);
  unsigned short* t2f16 = (unsigned short*)(ws + 24 * MB);
  unsigned short* h0    = (unsigned short*)(ws + 64 * MB);
  unsigned short* h1    = (unsigned short*)(ws + 128 * MB);
  unsigned short* We1t0 = (unsigned short*)(ws + 64 * MB);
  unsigned short* We2t0 = (unsigned short*)(ws + 80 * MB);
  unsigned short* feat16= (unsigned short*)(ws + 88 * MB);
  unsigned short* eob   = (unsigned short*)(ws + 120 * MB);
  unsigned short* W1t0  = (unsigned short*)(ws + 192 * MB);
  unsigned short* W1t1  = (unsigned short*)(ws + 196 * MB);
  unsigned short* W2t0  = (unsigned short*)(ws + 200 * MB);
  unsigned short* W2t1  = (unsigned short*)(ws + 204 * MB);
  float* gbuf = (float*)(ws + 192 * MB);
  unsigned short* tW1t = (unsigned short*)(ws + 192 * MB);
  unsigned short* tW2t = (unsigned short*)(ws + 193 * MB);
  char* small = ws + 208 * MB;
  int*   counts    = (int*)  (small);
  int*   offs      = (int*)  (small + 1024);
  int*   chunkCnt  = (int*)  (small + 2048);
  int*   chunkBase = (int*)  (small + 2048 + 4096);
  int*   topkIdx   = (int*)  (small + 16384);
  float* topkW     = (float*)(small + 16384 + 196608);
  int*   pairRow   = (int*)  (small + 16384 + 2 * 196608);
  float* pairW     = (float*)(small + 16384 + 3 * 196608);
  int*   rowPos    = (int*)  (small + 16384 + 4 * 196608);

  const dim3 blk(256, 1, 1);

  // input conversion + encoder GEMM1: h = concat @ W1 + b1 (fp16 split, 3 terms)
  convx_k<<<dim3(16384, 1, 1), blk, 0, stream>>>(embP, embR, x0, x1);
  transp_k<2,0><<<dim3(DIN/32, DHID/32, 1), blk, 0, stream>>>(encW1, W1t0, W1t1, nullptr, DIN, DHID);
  mgemm_k<1,0,0,32,DHID/128,0><<<dim3((BATCH/128)*(DHID/128), 1, 1), blk, 0, stream>>>(
      x0, x1, W1t0, W1t1, encB1, nullptr, h0, h1,
      nullptr, nullptr, nullptr, nullptr, nullptr, BATCH, DHID, DIN);
  ln_pair_k<DHID, true><<<dim3(BATCH, 1, 1), blk, 0, stream>>>(h0, h1, ln1g, ln1b);

  // encoder GEMM2: feat = h @ W2 + b2 (fp16 split, 3 terms) -> fp32
  transp_k<2,0><<<dim3(DHID/32, DIN/32, 1), blk, 0, stream>>>(encW2, W2t0, W2t1, nullptr, DHID, DIN);
  mgemm_k<1,0,3,32,DIN/128,0><<<dim3((BATCH/128)*(DIN/128), 1, 1), blk, 0, stream>>>(
      h0, h1, W2t0, W2t1, encB2, feat, nullptr, nullptr,
      nullptr, nullptr, nullptr, nullptr, nullptr, BATCH, DIN, DHID);
  // feat LN: fp32 in-place + fused fp16 mirror for the expert path
  ln_k<DIN, false, true><<<dim3(BATCH, 1, 1), blk, 0, stream>>>(feat, ln2g, ln2b, feat16);

  // gate (fp32 vector path on fp32 feat) — no global atomics anywhere
  gemm32_k<true><<<dim3(BATCH/128, 1, 1), blk, 0, stream>>>(
      feat, gW1, gb1, gbuf, taskPtr, BATCH, 128, DIN);
  gate_topk_k<<<dim3(BATCH/4, 1, 1), blk, 0, stream>>>(
      gbuf, gW2, gb2, taskPtr, out + BATCH + 1, topkIdx, topkW);
  hist_k<<<dim3(BATCH/256, 1, 1), blk, 0, stream>>>(topkIdx, chunkCnt);
  scanB_k<<<dim3(1, 1, 1), dim3(64, 1, 1), 0, stream>>>(chunkCnt, counts, offs, chunkBase);
  fill2_k<<<dim3(BATCH/256, 1, 1), blk, 0, stream>>>(topkIdx, topkW, chunkBase,
                                                     pairRow, pairW, rowPos);

  // expert weights in fp16 (h region free now)
  transp_k<1,0><<<dim3(DIN/32, EXPSZ/32, NEXP), blk, 0, stream>>>(We1, We1t0, nullptr, nullptr, DIN, EXPSZ);
  transp_k<1,0><<<dim3(EXPSZ/32, EXPSZ/32, NEXP), blk, 0, stream>>>(We2, We2t0, nullptr, nullptr, EXPSZ, EXPSZ);

  // expert GEMM1: e1 = relu(feat16[pairRow] @ We1[e] + be1)  (plain fp16)
  mgemm_k<0,1,1,64,EXPSZ/128,0><<<dim3((BATCH/128)*(EXPSZ/128), 1, NEXP), blk, 0, stream>>>(
      feat16, nullptr, We1t0, nullptr, be1, nullptr, e1b, nullptr,
      pairRow, nullptr, counts, offs, nullptr, NPAIR, EXPSZ, DIN);
  // expert GEMM2: eo = w_p * (e1 @ We2[e] + be2)  (plain fp16)
  mgemm_k<0,2,2,64,EXPSZ/128,0><<<dim3((BATCH/128)*(EXPSZ/128), 1, NEXP), blk, 0, stream>>>(
      e1b, nullptr, We2t0, nullptr, be2, nullptr, eob, nullptr,
      nullptr, pairW, counts, offs, nullptr, NPAIR, EXPSZ, EXPSZ);
  mixreduce_k<<<dim3(BATCH, 1, 1), blk, 0, stream>>>(eob, rowPos, mix16);

  // towers (plain fp16 MFMA, task-indexed weights/bias)
  transp_k<1,1><<<dim3(EXPSZ/32, 256/32, 1), blk, 0, stream>>>(tW1, tW1t, nullptr, taskPtr, EXPSZ, 256);
  transp_k<1,1><<<dim3(256/32, 128/32, 1), blk, 0, stream>>>(tW2, tW2t, nullptr, taskPtr, 256, 128);
  mgemm_k<0,0,1,64,2,1><<<dim3((BATCH/128)*2, 1, 1), blk, 0, stream>>>(
      mix16, nullptr, tW1t, nullptr, tb1, nullptr, t1f16, nullptr,
      nullptr, nullptr, nullptr, nullptr, taskPtr, BATCH, 256, EXPSZ);
  mgemm_k<0,0,1,64,1,1><<<dim3(BATCH/128, 1, 1), blk, 0, stream>>>(
      t1f16, nullptr, tW2t, nullptr, tb2, nullptr, t2f16, nullptr,
      nullptr, nullptr, nullptr, nullptr, taskPtr, BATCH, 128, 256);
  tower3_k<<<dim3(BATCH/4, 1, 1), blk, 0, stream>>>(t2f16, tW3, tb3, taskPtr, out);
}

// Round 13
// 1172.791 us; speedup vs baseline: 1.5467x; 1.0388x over previous
//
#include <hip/hip_runtime.h>

typedef __attribute__((ext_vector_type(8))) _Float16 f16x8;
typedef __attribute__((ext_vector_type(4))) float f32x4;

#define DEVINL __device__ __forceinline__

constexpr int BATCH = 16384;
constexpr int DIN   = 1024;
constexpr int DHID  = 2048;
constexpr int NEXP  = 16;
constexpr int EXPSZ = 512;
constexpr int NPAIR = BATCH * 3;

DEVINL unsigned short f2h(float v) {
  _Float16 h = (_Float16)v;
  return __builtin_bit_cast(unsigned short, h);
}
DEVINL float h2f(unsigned short u) {
  return (float)__builtin_bit_cast(_Float16, u);
}

DEVINL void gl2lds(const unsigned short* src, char* ldst) {
  __builtin_amdgcn_global_load_lds((const __attribute__((address_space(1))) void*)src,
                                   (__attribute__((address_space(3))) void*)ldst, 16, 0, 0);
}

// ---------------------------------------------------------------------------
// fp16 split-MFMA GEMM, 128x128 tile, 4 waves (2x2 of 64x64), 16x16x32 f16.
// Operands staged via global_load_lds (fragment-contiguous LDS). 1D grid
// (x = NXT*NYT tiles, z = expert); row-tiles round-robined across XCDs,
// col-tiles consecutive within an XCD (load-balanced under early-exit +
// A-panel L2 reuse; bijective for NXT%8==0 — speed-only).
// OCCUPANCY NOTE (r11 lesson): SPLIT kernels MUST stay at 2 blocks/CU.
// At 3 blocks/CU the L2 working set (staging panels + partially-filled
// epilogue write lines) overflows the 4MB/XCD L2: WRITE_SIZE 208MB->1GB,
// MfmaUtil 25%->13%, 2x slower. Occupancy is not monotonic here.
// BK=64 for SPLIT (r13): halves barrier count vs BK=32; 64KB LDS keeps
// 2 blocks/CU (128 <= 160 KB), so m132's occupancy-drop failure mode
// does not apply.
// SPLIT=1: v = c0 + c1/2048 (c1 stored x2048). 3 MFMA terms. SPLIT=0: fp16.
// AMODE: 0 linear A rows; 1 gather via pairRow; 2 pair-linear.
// TASK:  bias += (*taskPtr)*N (task-indexed bias; B pre-extracted).
// EPI:   0 +bias -> fp16 hi/lo pair; 1 +bias,relu -> fp16;
//        2 +bias,*pairW -> fp16; 3 +bias -> fp32; 4 +bias,relu -> fp32.
// ---------------------------------------------------------------------------
template<int SPLIT, int AMODE, int EPI, int BK, int NYT, int TASK>
__global__ __launch_bounds__(256, SPLIT ? 2 : 3)
void mgemm_k(const unsigned short* __restrict__ A0p,
             const unsigned short* __restrict__ A1p,
             const unsigned short* __restrict__ B0p,
             const unsigned short* __restrict__ B1p,
             const float* __restrict__ biasb,
             float* __restrict__ Cf, unsigned short* __restrict__ Cb0,
             unsigned short* __restrict__ Cb1,
             const int* __restrict__ pairRow, const float* __restrict__ pairW,
             const int* __restrict__ counts, const int* __restrict__ offs,
             const int* __restrict__ taskPtr,
             int M, int N, int K)
{
  constexpr int KG = BK / 8;
  constexpr int UNITS = 128 * KG;
  constexpr int ISS = UNITS / 256;
  constexpr int NKK = BK / 32;
  constexpr int NARR = SPLIT ? 4 : 2;
  constexpr bool EXPERT = (AMODE == 1 || AMODE == 2);
  __shared__ char smem[NARR * UNITS * 16];
  char* sA0 = smem;
  char* sA1 = smem + UNITS * 16;                    // iff SPLIT
  char* sB0 = smem + (SPLIT ? 2 : 1) * UNITS * 16;
  char* sB1 = smem + 3 * UNITS * 16;                // iff SPLIT

  int Mloc = M, rowBase = 0;
  const unsigned short* b0 = B0p;
  const unsigned short* b1 = B1p;
  const float* bias = biasb;
  if (EXPERT) {
    const int e = blockIdx.z;
    Mloc = counts[e];
    rowBase = offs[e];
    const size_t eo = (size_t)e * (size_t)K * N;
    b0 = B0p + eo;
    if (SPLIT) b1 = B1p + eo;
    bias = biasb + (size_t)e * N;
  }
  if (TASK) bias = biasb + (size_t)(*taskPtr) * N;

  // round-robin row-tiles over XCDs; col-tiles consecutive within XCD
  const int xcd = (int)blockIdx.x & 7;
  const int j   = (int)blockIdx.x >> 3;
  const int tile0 = (xcd + 8 * (j / NYT)) * 128;
  const int col0  = (j % NYT) * 128;
  if (tile0 >= Mloc) return;

  const int tid = threadIdx.x;
  const int lane = tid & 63;
  const int wr = ((tid >> 6) >> 1) * 64;
  const int wc = ((tid >> 6) & 1) * 64;
  const int l15 = lane & 15;
  const int lg = lane >> 4;

  // per-thread staging row (fixed across K)
  const int srow = tid & 127;
  size_t aoff;
  if (AMODE == 0) {
    aoff = (size_t)(tile0 + srow) * K;
  } else if (AMODE == 1) {
    int p = rowBase + tile0 + srow; p = p < NPAIR - 1 ? p : NPAIR - 1;
    aoff = (size_t)pairRow[p] * K;
  } else {
    int p = rowBase + tile0 + srow; p = p < NPAIR - 1 ? p : NPAIR - 1;
    aoff = (size_t)p * K;
  }
  const size_t boff = (size_t)(col0 + srow) * K;

  f32x4 acc[4][4];
  f32x4 acc2[4][4];
  #pragma unroll
  for (int m = 0; m < 4; ++m)
    #pragma unroll
    for (int n = 0; n < 4; ++n) {
      acc[m][n] = f32x4{0.f, 0.f, 0.f, 0.f};
      if (SPLIT) acc2[m][n] = f32x4{0.f, 0.f, 0.f, 0.f};
    }

  for (int kt = 0; kt < K; kt += BK) {
    #pragma unroll
    for (int it = 0; it < ISS; ++it) {
      const int uo = (it * 256 + (tid & 192)) * 16;   // wave-uniform LDS base
      const int ko = kt + (it * 2 + (tid >> 7)) * 8;
      gl2lds(A0p + aoff + ko, sA0 + uo);
      if (SPLIT) gl2lds(A1p + aoff + ko, sA1 + uo);
      gl2lds(b0 + boff + ko, sB0 + uo);
      if (SPLIT) gl2lds(b1 + boff + ko, sB1 + uo);
    }
    __syncthreads();
    #pragma unroll
    for (int kk = 0; kk < NKK; ++kk) {
      const int g = kk * 4 + lg;
      f16x8 b0f[4], b1f[4];
      #pragma unroll
      for (int n = 0; n < 4; ++n) {
        const size_t off = (size_t)(g * 128 + wc + n * 16 + l15) * 16;
        b0f[n] = *(const f16x8*)(sB0 + off);
        if (SPLIT) b1f[n] = *(const f16x8*)(sB1 + off);
      }
      #pragma unroll
      for (int m = 0; m < 4; ++m) {
        const size_t ao = (size_t)(g * 128 + wr + m * 16 + l15) * 16;
        const f16x8 a0 = *(const f16x8*)(sA0 + ao);
        f16x8 a1;
        if (SPLIT) a1 = *(const f16x8*)(sA1 + ao);
        #pragma unroll
        for (int n = 0; n < 4; ++n) {
          if (SPLIT) {
            acc2[m][n] = __builtin_amdgcn_mfma_f32_16x16x32_f16(a1, b0f[n], acc2[m][n], 0, 0, 0);
            acc2[m][n] = __builtin_amdgcn_mfma_f32_16x16x32_f16(a0, b1f[n], acc2[m][n], 0, 0, 0);
          }
          acc[m][n] = __builtin_amdgcn_mfma_f32_16x16x32_f16(a0, b0f[n], acc[m][n], 0, 0, 0);
        }
      }
    }
    __syncthreads();
  }

  // epilogue. C/D mapping: col = lane&15, row = (lane>>4)*4 + j  [m89-verified]
  #pragma unroll
  for (int n = 0; n < 4; ++n) {
    const int cn = col0 + wc + n * 16 + l15;
    const float bv = bias[cn];
    #pragma unroll
    for (int m = 0; m < 4; ++m) {
      const int r0 = wr + m * 16 + ((lane >> 4) << 2);
      #pragma unroll
      for (int jj = 0; jj < 4; ++jj) {
        const int rm = tile0 + r0 + jj;
        if (EXPERT && rm >= Mloc) continue;
        float v = acc[m][n][jj];
        if (SPLIT) v += acc2[m][n][jj] * (1.f / 2048.f);
        v += bv;
        const size_t ci = (size_t)(EXPERT ? (rowBase + rm) : rm) * N + cn;
        if (EPI == 0) {
          const unsigned short h0 = f2h(v);
          Cb0[ci] = h0;
          Cb1[ci] = f2h((v - h2f(h0)) * 2048.f);
        } else if (EPI == 1) {
          Cb0[ci] = f2h(fmaxf(v, 0.f));
        } else if (EPI == 2) {
          Cb0[ci] = f2h(v * pairW[rowBase + rm]);
        } else if (EPI == 3) {
          Cf[ci] = v;
        } else {
          Cf[ci] = fmaxf(v, 0.f);
        }
      }
    }
  }
}

// ---------------------------------------------------------------------------
// transpose+convert: src fp32 [z][R][C] -> fp16 level arrays [z][C][R].
// LEV=2: level-1 stored x2048. TASK: src += (*taskPtr)*R*C (extract task t).
// ---------------------------------------------------------------------------
template<int LEV, int TASK>
__global__ __launch_bounds__(256)
void transp_k(const float* __restrict__ src, unsigned short* __restrict__ d0,
              unsigned short* __restrict__ d1, const int* __restrict__ taskPtr,
              int R, int C)
{
  __shared__ float tle[32][33];
  size_t bb = (size_t)blockIdx.z * R * C;
  if (TASK) bb = (size_t)(*taskPtr) * R * C;
  const int r0 = blockIdx.x * 32, c0 = blockIdx.y * 32;
  const int x = threadIdx.x & 31, y = threadIdx.x >> 5;
  #pragma unroll
  for (int i = 0; i < 32; i += 8)
    tle[y + i][x] = src[bb + (size_t)(r0 + y + i) * C + (c0 + x)];
  __syncthreads();
  const size_t db = TASK ? 0 : (size_t)blockIdx.z * R * C;
  #pragma unroll
  for (int i = 0; i < 32; i += 8) {
    const float v = tle[x][y + i];
    const size_t di = db + (size_t)(c0 + y + i) * R + (r0 + x);
    const unsigned short h0 = f2h(v);
    d0[di] = h0;
    if (LEV > 1) d1[di] = f2h((v - h2f(h0)) * 2048.f);
  }
}

// concat(embP,embR) fp32 -> fp16 hi/lo pair arrays [B][1024]
__global__ __launch_bounds__(256)
void convx_k(const float* __restrict__ eP, const float* __restrict__ eR,
             unsigned short* __restrict__ x0, unsigned short* __restrict__ x1)
{
  const size_t u = (size_t)blockIdx.x * 256 + threadIdx.x;  // 4-elem units
  const size_t row = u >> 8;
  const int c4 = (int)(u & 255) * 4;
  const float* s = (c4 < 512) ? (eP + row * 512 + c4) : (eR + row * 512 + (c4 - 512));
  const float4 v = *(const float4*)s;
  const float vv[4] = {v.x, v.y, v.z, v.w};
  ushort4 h4, l4;
  unsigned short* hp = (unsigned short*)&h4;
  unsigned short* lp = (unsigned short*)&l4;
  #pragma unroll
  for (int j = 0; j < 4; ++j) {
    const unsigned short h0 = f2h(vv[j]);
    hp[j] = h0;
    lp[j] = f2h((vv[j] - h2f(h0)) * 2048.f);
  }
  *(ushort4*)(x0 + row * 1024 + c4) = h4;
  *(ushort4*)(x1 + row * 1024 + c4) = l4;
}

// ---------------------------------------------------------------------------
// In-place LayerNorm (+ optional relu) over fp16 hi/lo pair rows (fp32 math).
// ---------------------------------------------------------------------------
template<int COLS, bool RELU>
__global__ __launch_bounds__(256)
void ln_pair_k(unsigned short* __restrict__ h0, unsigned short* __restrict__ h1,
               const float* __restrict__ g, const float* __restrict__ b)
{
  constexpr int PER = COLS / 256;
  const size_t row = blockIdx.x;
  unsigned short* r0 = h0 + row * COLS;
  unsigned short* r1 = h1 + row * COLS;
  const int c0 = threadIdx.x * PER;
  float v[PER];
  float s = 0.f, s2 = 0.f;
  #pragma unroll
  for (int i = 0; i < PER; i += 4) {
    const ushort4 a = *(const ushort4*)(r0 + c0 + i);
    const ushort4 c = *(const ushort4*)(r1 + c0 + i);
    v[i+0] = h2f(a.x) + h2f(c.x) * (1.f/2048.f);
    v[i+1] = h2f(a.y) + h2f(c.y) * (1.f/2048.f);
    v[i+2] = h2f(a.z) + h2f(c.z) * (1.f/2048.f);
    v[i+3] = h2f(a.w) + h2f(c.w) * (1.f/2048.f);
  }
  #pragma unroll
  for (int i = 0; i < PER; ++i) { s += v[i]; s2 += v[i] * v[i]; }
  #pragma unroll
  for (int o = 1; o < 64; o <<= 1) { s += __shfl_xor(s, o); s2 += __shfl_xor(s2, o); }
  __shared__ float ss[4], ss2[4];
  const int w = threadIdx.x >> 6;
  if ((threadIdx.x & 63) == 0) { ss[w] = s; ss2[w] = s2; }
  __syncthreads();
  s  = ss[0] + ss[1] + ss[2] + ss[3];
  s2 = ss2[0] + ss2[1] + ss2[2] + ss2[3];
  const float mu = s * (1.f / COLS);
  const float var = s2 * (1.f / COLS) - mu * mu;
  const float rs = rsqrtf(var + 1e-5f);
  #pragma unroll
  for (int i = 0; i < PER; i += 4) {
    ushort4 a4, c4v;
    unsigned short* ap = (unsigned short*)&a4;
    unsigned short* cp = (unsigned short*)&c4v;
    #pragma unroll
    for (int jq = 0; jq < 4; ++jq) {
      const int c = c0 + i + jq;
      float y = (v[i+jq] - mu) * rs * g[c] + b[c];
      if (RELU) y = fmaxf(y, 0.f);
      const unsigned short hh = f2h(y);
      ap[jq] = hh;
      cp[jq] = f2h((y - h2f(hh)) * 2048.f);
    }
    *(ushort4*)(r0 + c0 + i) = a4;
    *(ushort4*)(r1 + c0 + i) = c4v;
  }
}

// ---------------------------------------------------------------------------
// gate: logits = g @ gW2[t] + gb2[t]; top-3 softmax; NO global atomics.
// ---------------------------------------------------------------------------
__global__ __launch_bounds__(256)
void gate_topk_k(const float* __restrict__ g, const float* __restrict__ gW2,
                 const float* __restrict__ gb2, const int* __restrict__ taskPtr,
                 float* __restrict__ gatesOut, int* __restrict__ topkIdx,
                 float* __restrict__ topkW)
{
  const int t = *taskPtr;
  const float* W = gW2 + (size_t)t * 128 * 16;
  const float* bias = gb2 + (size_t)t * 16;
  const int lane = threadIdx.x & 63;
  const int row = blockIdx.x * 4 + (threadIdx.x >> 6);
  const float* gr = g + (size_t)row * 128;
  const int e = lane & 15;
  const int q = lane >> 4;
  float s = 0.f;
  for (int j = q * 32; j < q * 32 + 32; ++j) s = fmaf(gr[j], W[j * 16 + e], s);
  s += __shfl_xor(s, 16);
  s += __shfl_xor(s, 32);
  s += bias[e];
  float logits[16];
  #pragma unroll
  for (int i = 0; i < 16; ++i) logits[i] = __shfl(s, i);
  int i0 = 0; float v0 = logits[0];
  #pragma unroll
  for (int i = 1; i < 16; ++i) if (logits[i] > v0) { v0 = logits[i]; i0 = i; }
  int i1 = -1; float v1 = -3.4e38f;
  #pragma unroll
  for (int i = 0; i < 16; ++i) if (i != i0 && logits[i] > v1) { v1 = logits[i]; i1 = i; }
  int i2 = -1; float v2 = -3.4e38f;
  #pragma unroll
  for (int i = 0; i < 16; ++i) if (i != i0 && i != i1 && logits[i] > v2) { v2 = logits[i]; i2 = i; }
  const float ex1 = expf(v1 - v0);
  const float ex2 = expf(v2 - v0);
  const float inv = 1.f / (1.f + ex1 + ex2);
  const float p0 = inv, p1 = ex1 * inv, p2 = ex2 * inv;
  if (lane < 16) {
    const float gv = (lane == i0) ? p0 : (lane == i1) ? p1 : (lane == i2) ? p2 : 0.f;
    gatesOut[(size_t)row * 16 + lane] = gv;
  }
  if (lane == 0) {
    topkIdx[row * 3 + 0] = i0; topkIdx[row * 3 + 1] = i1; topkIdx[row * 3 + 2] = i2;
    topkW [row * 3 + 0] = p0; topkW [row * 3 + 1] = p1; topkW [row * 3 + 2] = p2;
  }
}

// per-chunk expert histogram (LDS atomics only)
__global__ __launch_bounds__(256)
void hist_k(const int* __restrict__ topkIdx, int* __restrict__ chunkCnt)
{
  __shared__ int lc[NEXP];
  if (threadIdx.x < NEXP) lc[threadIdx.x] = 0;
  __syncthreads();
  const int row = blockIdx.x * 256 + threadIdx.x;
  #pragma unroll
  for (int k = 0; k < 3; ++k) atomicAdd(&lc[topkIdx[row * 3 + k]], 1);
  __syncthreads();
  if (threadIdx.x < NEXP) chunkCnt[blockIdx.x * NEXP + threadIdx.x] = lc[threadIdx.x];
}

// serial scan: counts/offs per expert + per-chunk bases
__global__ void scanB_k(const int* __restrict__ chunkCnt, int* __restrict__ counts,
                        int* __restrict__ offs, int* __restrict__ chunkBase)
{
  if (threadIdx.x == 0) {
    int tot[NEXP];
    for (int e = 0; e < NEXP; ++e) tot[e] = 0;
    for (int c = 0; c < 64; ++c)
      for (int e = 0; e < NEXP; ++e) tot[e] += chunkCnt[c * NEXP + e];
    int a = 0;
    for (int e = 0; e < NEXP; ++e) { offs[e] = a; counts[e] = tot[e]; a += tot[e]; }
    for (int e = 0; e < NEXP; ++e) {
      int b = offs[e];
      for (int c = 0; c < 64; ++c) { chunkBase[c * NEXP + e] = b; b += chunkCnt[c * NEXP + e]; }
    }
  }
}

// fill pair lists: LDS-atomic within-chunk offsets + precomputed chunk base
__global__ __launch_bounds__(256)
void fill2_k(const int* __restrict__ topkIdx, const float* __restrict__ topkW,
             const int* __restrict__ chunkBase, int* __restrict__ pairRow,
             float* __restrict__ pairW, int* __restrict__ rowPos)
{
  __shared__ int lc[NEXP];
  if (threadIdx.x < NEXP) lc[threadIdx.x] = 0;
  __syncthreads();
  const int row = blockIdx.x * 256 + threadIdx.x;
  #pragma unroll
  for (int k = 0; k < 3; ++k) {
    const int e = topkIdx[row * 3 + k];
    const int lofs = atomicAdd(&lc[e], 1);
    const int pos = chunkBase[blockIdx.x * NEXP + e] + lofs;
    pairRow[pos] = row;
    pairW[pos] = topkW[row * 3 + k];
    rowPos[row * 3 + k] = pos;
  }
}

// mix (fp16 out) = sum of the row's 3 eo slots
__global__ __launch_bounds__(256)
void mixreduce_k(const unsigned short* __restrict__ eo, const int* __restrict__ rowPos,
                 unsigned short* __restrict__ mix16)
{
  const size_t row = blockIdx.x;
  const size_t p0 = rowPos[row * 3 + 0];
  const size_t p1 = rowPos[row * 3 + 1];
  const size_t p2 = rowPos[row * 3 + 2];
  for (int c = threadIdx.x; c < EXPSZ; c += 256) {
    mix16[row * EXPSZ + c] = f2h(h2f(eo[p0 * EXPSZ + c]) + h2f(eo[p1 * EXPSZ + c])
                               + h2f(eo[p2 * EXPSZ + c]));
  }
}

__global__ __launch_bounds__(256)
void tower3_k(const unsigned short* __restrict__ t2, const float* __restrict__ tW3,
              const float* __restrict__ tb3, const int* __restrict__ taskPtr,
              float* __restrict__ out)
{
  const int t = *taskPtr;
  const float* w = tW3 + (size_t)t * 128;
  const float bias = tb3[t];
  const int lane = threadIdx.x & 63;
  const int row = blockIdx.x * 4 + (threadIdx.x >> 6);
  const unsigned short* x = t2 + (size_t)row * 128;
  float s = fmaf(h2f(x[lane]), w[lane], h2f(x[lane + 64]) * w[lane + 64]);
  #pragma unroll
  for (int o = 1; o < 64; o <<= 1) s += __shfl_xor(s, o);
  if (lane == 0) out[row] = 1.f / (1.f + expf(-(s + bias)));
  if (blockIdx.x == 0 && threadIdx.x == 0) out[BATCH] = (float)t;
}

// ---------------------------------------------------------------------------
extern "C" void kernel_launch(void* const* d_in, const int* in_sizes, int n_in,
                              void* d_out, int out_size, void* d_ws, size_t ws_size,
                              hipStream_t stream)
{
  (void)in_sizes; (void)n_in; (void)out_size; (void)ws_size;
  const float* embP  = (const float*)d_in[0];
  const float* embR  = (const float*)d_in[1];
  const float* encW1 = (const float*)d_in[2];
  const float* encB1 = (const float*)d_in[3];
  const float* ln1g  = (const float*)d_in[4];
  const float* ln1b  = (const float*)d_in[5];
  const float* encW2 = (const float*)d_in[6];
  const float* encB2 = (const float*)d_in[7];
  const float* ln2g  = (const float*)d_in[8];
  const float* ln2b  = (const float*)d_in[9];
  const float* gW1   = (const float*)d_in[10];
  const float* gb1   = (const float*)d_in[11];
  const float* gW2   = (const float*)d_in[12];
  const float* gb2   = (const float*)d_in[13];
  const float* We1   = (const float*)d_in[14];
  const float* be1   = (const float*)d_in[15];
  const float* We2   = (const float*)d_in[16];
  const float* be2   = (const float*)d_in[17];
  const float* tW1   = (const float*)d_in[18];
  const float* tb1   = (const float*)d_in[19];
  const float* tW2   = (const float*)d_in[20];
  const float* tb2   = (const float*)d_in[21];
  const float* tW3   = (const float*)d_in[22];
  const float* tb3   = (const float*)d_in[23];
  const int* taskPtr = (const int*)d_in[24];

  float* out = (float*)d_out;
  char* ws = (char*)d_ws;
  const size_t MB = 1ull << 20;

  // Lifetime-aliased workspace (peak ~209 MB):
  //  [0,64):   x0[0,32),x1[32,64) -> feat0[0,32),feat1[32,64)
  //            feat1 dead after gate -> mix16[32,48), t1f16[48,56), t2f16[56,60)
  //  [64,192): h0[64,128),h1[128,192) -> We1t0[64,80),We2t0[80,88),
  //            e1b[88,136), eob[136,184)
  //  [192,208): W1t0[192,196),W1t1[196,200) -> gbuf[192,200) -> tW1t,tW2t
  //             W2t0[200,204),W2t1[204,208) -> gW1t0[200,204),gW1t1[204,208)
  //  [208,~209): metadata
  unsigned short* x0    = (unsigned short*)(ws);
  unsigned short* x1    = (unsigned short*)(ws + 32 * MB);
  unsigned short* feat0 = (unsigned short*)(ws);
  unsigned short* feat1 = (unsigned short*)(ws + 32 * MB);
  unsigned short* mix16 = (unsigned short*)(ws + 32 * MB);
  unsigned short* t1f16 = (unsigned short*)(ws + 48 * MB);
  unsigned short* t2f16 = (unsigned short*)(ws + 56 * MB);
  unsigned short* h0    = (unsigned short*)(ws + 64 * MB);
  unsigned short* h1    = (unsigned short*)(ws + 128 * MB);
  unsigned short* We1t0 = (unsigned short*)(ws + 64 * MB);
  unsigned short* We2t0 = (unsigned short*)(ws + 80 * MB);
  unsigned short* e1b   = (unsigned short*)(ws + 88 * MB);
  unsigned short* eob   = (unsigned short*)(ws + 136 * MB);
  unsigned short* W1t0  = (unsigned short*)(ws + 192 * MB);
  unsigned short* W1t1  = (unsigned short*)(ws + 196 * MB);
  unsigned short* W2t0  = (unsigned short*)(ws + 200 * MB);
  unsigned short* W2t1  = (unsigned short*)(ws + 204 * MB);
  unsigned short* gW1t0 = (unsigned short*)(ws + 200 * MB);
  unsigned short* gW1t1 = (unsigned short*)(ws + 204 * MB);
  float* gbuf = (float*)(ws + 192 * MB);
  unsigned short* tW1t = (unsigned short*)(ws + 192 * MB);
  unsigned short* tW2t = (unsigned short*)(ws + 193 * MB);
  char* small = ws + 208 * MB;
  int*   counts    = (int*)  (small);
  int*   offs      = (int*)  (small + 1024);
  int*   chunkCnt  = (int*)  (small + 2048);
  int*   chunkBase = (int*)  (small + 2048 + 4096);
  int*   topkIdx   = (int*)  (small + 16384);
  float* topkW     = (float*)(small + 16384 + 196608);
  int*   pairRow   = (int*)  (small + 16384 + 2 * 196608);
  float* pairW     = (float*)(small + 16384 + 3 * 196608);
  int*   rowPos    = (int*)  (small + 16384 + 4 * 196608);

  const dim3 blk(256, 1, 1);

  // input conversion + encoder GEMM1: h = concat @ W1 + b1 (fp16 split, BK=64)
  convx_k<<<dim3(16384, 1, 1), blk, 0, stream>>>(embP, embR, x0, x1);
  transp_k<2,0><<<dim3(DIN/32, DHID/32, 1), blk, 0, stream>>>(encW1, W1t0, W1t1, nullptr, DIN, DHID);
  mgemm_k<1,0,0,64,DHID/128,0><<<dim3((BATCH/128)*(DHID/128), 1, 1), blk, 0, stream>>>(
      x0, x1, W1t0, W1t1, encB1, nullptr, h0, h1,
      nullptr, nullptr, nullptr, nullptr, nullptr, BATCH, DHID, DIN);
  ln_pair_k<DHID, true><<<dim3(BATCH, 1, 1), blk, 0, stream>>>(h0, h1, ln1g, ln1b);

  // encoder GEMM2: feat = h @ W2 + b2 (fp16 split, BK=64) -> fp16 pair
  transp_k<2,0><<<dim3(DHID/32, DIN/32, 1), blk, 0, stream>>>(encW2, W2t0, W2t1, nullptr, DHID, DIN);
  mgemm_k<1,0,0,64,DIN/128,0><<<dim3((BATCH/128)*(DIN/128), 1, 1), blk, 0, stream>>>(
      h0, h1, W2t0, W2t1, encB2, nullptr, feat0, feat1,
      nullptr, nullptr, nullptr, nullptr, nullptr, BATCH, DIN, DHID);
  ln_pair_k<DIN, false><<<dim3(BATCH, 1, 1), blk, 0, stream>>>(feat0, feat1, ln2g, ln2b);

  // gate: g = relu(feat @ gW1[t] + gb1[t])  (fp16 split MFMA -> fp32 gbuf)
  transp_k<2,1><<<dim3(DIN/32, 128/32, 1), blk, 0, stream>>>(gW1, gW1t0, gW1t1, taskPtr, DIN, 128);
  mgemm_k<1,0,4,64,1,1><<<dim3(BATCH/128, 1, 1), blk, 0, stream>>>(
      feat0, feat1, gW1t0, gW1t1, gb1, gbuf, nullptr, nullptr,
      nullptr, nullptr, nullptr, nullptr, taskPtr, BATCH, 128, DIN);
  gate_topk_k<<<dim3(BATCH/4, 1, 1), blk, 0, stream>>>(
      gbuf, gW2, gb2, taskPtr, out + BATCH + 1, topkIdx, topkW);
  hist_k<<<dim3(BATCH/256, 1, 1), blk, 0, stream>>>(topkIdx, chunkCnt);
  scanB_k<<<dim3(1, 1, 1), dim3(64, 1, 1), 0, stream>>>(chunkCnt, counts, offs, chunkBase);
  fill2_k<<<dim3(BATCH/256, 1, 1), blk, 0, stream>>>(topkIdx, topkW, chunkBase,
                                                     pairRow, pairW, rowPos);

  // expert weights in fp16 (h region free now)
  transp_k<1,0><<<dim3(DIN/32, EXPSZ/32, NEXP), blk, 0, stream>>>(We1, We1t0, nullptr, nullptr, DIN, EXPSZ);
  transp_k<1,0><<<dim3(EXPSZ/32, EXPSZ/32, NEXP), blk, 0, stream>>>(We2, We2t0, nullptr, nullptr, EXPSZ, EXPSZ);

  // expert GEMM1: e1 = relu(feat0[pairRow] @ We1[e] + be1)  (plain fp16)
  mgemm_k<0,1,1,64,EXPSZ/128,0><<<dim3((BATCH/128)*(EXPSZ/128), 1, NEXP), blk, 0, stream>>>(
      feat0, nullptr, We1t0, nullptr, be1, nullptr, e1b, nullptr,
      pairRow, nullptr, counts, offs, nullptr, NPAIR, EXPSZ, DIN);
  // expert GEMM2: eo = w_p * (e1 @ We2[e] + be2)  (plain fp16)
  mgemm_k<0,2,2,64,EXPSZ/128,0><<<dim3((BATCH/128)*(EXPSZ/128), 1, NEXP), blk, 0, stream>>>(
      e1b, nullptr, We2t0, nullptr, be2, nullptr, eob, nullptr,
      nullptr, pairW, counts, offs, nullptr, NPAIR, EXPSZ, EXPSZ);
  mixreduce_k<<<dim3(BATCH, 1, 1), blk, 0, stream>>>(eob, rowPos, mix16);

  // towers (plain fp16 MFMA, task-indexed weights/bias)
  transp_k<1,1><<<dim3(EXPSZ/32, 256/32, 1), blk, 0, stream>>>(tW1, tW1t, nullptr, taskPtr, EXPSZ, 256);
  transp_k<1,1><<<dim3(256/32, 128/32, 1), blk, 0, stream>>>(tW2, tW2t, nullptr, taskPtr, 256, 128);
  mgemm_k<0,0,1,64,2,1><<<dim3((BATCH/128)*2, 1, 1), blk, 0, stream>>>(
      mix16, nullptr, tW1t, nullptr, tb1, nullptr, t1f16, nullptr,
      nullptr, nullptr, nullptr, nullptr, taskPtr, BATCH, 256, EXPSZ);
  mgemm_k<0,0,1,64,1,1><<<dim3(BATCH/128, 1, 1), blk, 0, stream>>>(
      t1f16, nullptr, tW2t, nullptr, tb2, nullptr, t2f16, nullptr,
      nullptr, nullptr, nullptr, nullptr, taskPtr, BATCH, 128, 256);
  tower3_k<<<dim3(BATCH/4, 1, 1), blk, 0, stream>>>(t2f16, tW3, tb3, taskPtr, out);
}

// Round 14
// 1110.386 us; speedup vs baseline: 1.6337x; 1.0562x over previous
//
#include <hip/hip_runtime.h>

typedef __attribute__((ext_vector_type(8))) _Float16 f16x8;
typedef __attribute__((ext_vector_type(4))) float f32x4;

#define DEVINL __device__ __forceinline__

constexpr int BATCH = 16384;
constexpr int DIN   = 1024;
constexpr int DHID  = 2048;
constexpr int NEXP  = 16;
constexpr int EXPSZ = 512;
constexpr int NPAIR = BATCH * 3;

DEVINL unsigned short f2h(float v) {
  _Float16 h = (_Float16)v;
  return __builtin_bit_cast(unsigned short, h);
}
DEVINL float h2f(unsigned short u) {
  return (float)__builtin_bit_cast(_Float16, u);
}

DEVINL void gl2lds(const unsigned short* src, char* ldst) {
  __builtin_amdgcn_global_load_lds((const __attribute__((address_space(1))) void*)src,
                                   (__attribute__((address_space(3))) void*)ldst, 16, 0, 0);
}

// ---------------------------------------------------------------------------
// fp16 split-MFMA GEMM, 128x128 tile, 4 waves (2x2 of 64x64), 16x16x32 f16.
// B staged via global_load_lds from fp16 level arrays Bt[N][K].
// A side (ASTAGE):
//   0 = fp16 level arrays via global_load_lds (expert/tower path)
//   1 = fp32 source, reg-staged: load float4s, split in-register to fp16
//       level(s), ds_write fragment-order. (r14: beats pre-materialized
//       pair — r7 339us vs r8-12 358-373us; conversion VALU is off the
//       critical path, pair materialization traffic is not.)
// 1D grid (x = NXT*NYT tiles, z = expert); row-tiles round-robined across
// XCDs, col-tiles consecutive within an XCD (r10: load-balanced under
// early-exit + A-panel L2 reuse; bijective for NXT%8==0 — speed-only).
// OCCUPANCY (r11): SPLIT kernels stay at 2 blocks/CU. 3 blocks/CU
// overflows the 4MB/XCD L2 (WRITE 208MB->1GB, MfmaUtil 25->13%).
// BK (r13): 64 regressed the encoder (FETCH 181->284MB); use 32 for SPLIT.
// SPLIT=1: v = c0 + c1/2048 (c1 stored x2048). 3 MFMA terms. SPLIT=0: fp16.
// AMODE: 0 linear A rows; 1 gather via pairRow; 2 pair-linear;
//        3 concat(embP,embR) fp32 rows (requires ASTAGE=1).
// TASK:  bias += (*taskPtr)*N (task-indexed bias; B pre-extracted).
// EPI:   0 +bias -> fp16 hi/lo pair; 1 +bias,relu -> fp16;
//        2 +bias,*pairW -> fp16; 3 +bias -> fp32; 4 +bias,relu -> fp32.
// ---------------------------------------------------------------------------
template<int SPLIT, int ASTAGE, int AMODE, int EPI, int BK, int NYT, int TASK>
__global__ __launch_bounds__(256, SPLIT ? 2 : 3)
void mgemm_k(const unsigned short* __restrict__ A0p,
             const unsigned short* __restrict__ A1p,
             const float* __restrict__ Af0, const float* __restrict__ Af1,
             const unsigned short* __restrict__ B0p,
             const unsigned short* __restrict__ B1p,
             const float* __restrict__ biasb,
             float* __restrict__ Cf, unsigned short* __restrict__ Cb0,
             unsigned short* __restrict__ Cb1,
             const int* __restrict__ pairRow, const float* __restrict__ pairW,
             const int* __restrict__ counts, const int* __restrict__ offs,
             const int* __restrict__ taskPtr,
             int M, int N, int K)
{
  constexpr int KG = BK / 8;
  constexpr int UNITS = 128 * KG;
  constexpr int ISS = UNITS / 256;
  constexpr int NKK = BK / 32;
  constexpr int NARR = SPLIT ? 4 : 2;
  constexpr bool EXPERT = (AMODE == 1 || AMODE == 2);
  __shared__ char smem[NARR * UNITS * 16];
  char* sA0 = smem;
  char* sA1 = smem + UNITS * 16;                    // iff SPLIT
  char* sB0 = smem + (SPLIT ? 2 : 1) * UNITS * 16;
  char* sB1 = smem + 3 * UNITS * 16;                // iff SPLIT

  int Mloc = M, rowBase = 0;
  const unsigned short* b0 = B0p;
  const unsigned short* b1 = B1p;
  const float* bias = biasb;
  if (EXPERT) {
    const int e = blockIdx.z;
    Mloc = counts[e];
    rowBase = offs[e];
    const size_t eo = (size_t)e * (size_t)K * N;
    b0 = B0p + eo;
    if (SPLIT) b1 = B1p + eo;
    bias = biasb + (size_t)e * N;
  }
  if (TASK) bias = biasb + (size_t)(*taskPtr) * N;

  // round-robin row-tiles over XCDs; col-tiles consecutive within XCD
  const int xcd = (int)blockIdx.x & 7;
  const int j   = (int)blockIdx.x >> 3;
  const int tile0 = (xcd + 8 * (j / NYT)) * 128;
  const int col0  = (j % NYT) * 128;
  if (tile0 >= Mloc) return;

  const int tid = threadIdx.x;
  const int lane = tid & 63;
  const int wr = ((tid >> 6) >> 1) * 64;
  const int wc = ((tid >> 6) & 1) * 64;
  const int l15 = lane & 15;
  const int lg = lane >> 4;

  // per-thread staging row (fixed across K)
  const int srow = tid & 127;
  size_t aoff = 0;
  const float* aF = nullptr;
  const float* aP = nullptr;
  const float* aR = nullptr;
  if (ASTAGE) {
    if (AMODE == 3) {
      aP = Af0 + (size_t)(tile0 + srow) * 512;
      aR = Af1 + (size_t)(tile0 + srow) * 512;
    } else {
      aF = Af0 + (size_t)(tile0 + srow) * K;
    }
  } else if (AMODE == 0) {
    aoff = (size_t)(tile0 + srow) * K;
  } else if (AMODE == 1) {
    int p = rowBase + tile0 + srow; p = p < NPAIR - 1 ? p : NPAIR - 1;
    aoff = (size_t)pairRow[p] * K;
  } else {
    int p = rowBase + tile0 + srow; p = p < NPAIR - 1 ? p : NPAIR - 1;
    aoff = (size_t)p * K;
  }
  const size_t boff = (size_t)(col0 + srow) * K;

  f32x4 acc[4][4];
  f32x4 acc2[4][4];
  #pragma unroll
  for (int m = 0; m < 4; ++m)
    #pragma unroll
    for (int n = 0; n < 4; ++n) {
      acc[m][n] = f32x4{0.f, 0.f, 0.f, 0.f};
      if (SPLIT) acc2[m][n] = f32x4{0.f, 0.f, 0.f, 0.f};
    }

  for (int kt = 0; kt < K; kt += BK) {
    if (ASTAGE) {
      // reg-stage A: fp32 load, split to fp16 level(s), ds_write fragments
      #pragma unroll
      for (int it = 0; it < ISS; ++it) {
        const int u = it * 256 + tid;
        const int ko = kt + (u >> 7) * 8;
        const float* s;
        if (AMODE == 3) s = (ko < 512) ? (aP + ko) : (aR + (ko - 512));
        else            s = aF + ko;
        const float4 x0 = *(const float4*)s;
        const float4 x1 = *(const float4*)(s + 4);
        const float vv[8] = {x0.x, x0.y, x0.z, x0.w, x1.x, x1.y, x1.z, x1.w};
        f16x8 q0, q1;
        #pragma unroll
        for (int jq = 0; jq < 8; ++jq) {
          const _Float16 c0 = (_Float16)vv[jq];
          q0[jq] = c0;
          if (SPLIT) q1[jq] = (_Float16)((vv[jq] - (float)c0) * 2048.f);
        }
        *(f16x8*)(sA0 + (size_t)u * 16) = q0;
        if (SPLIT) *(f16x8*)(sA1 + (size_t)u * 16) = q1;
      }
    }
    #pragma unroll
    for (int it = 0; it < ISS; ++it) {
      const int uo = (it * 256 + (tid & 192)) * 16;   // wave-uniform LDS base
      const int ko = kt + (it * 2 + (tid >> 7)) * 8;
      if (!ASTAGE) {
        gl2lds(A0p + aoff + ko, sA0 + uo);
        if (SPLIT) gl2lds(A1p + aoff + ko, sA1 + uo);
      }
      gl2lds(b0 + boff + ko, sB0 + uo);
      if (SPLIT) gl2lds(b1 + boff + ko, sB1 + uo);
    }
    __syncthreads();
    #pragma unroll
    for (int kk = 0; kk < NKK; ++kk) {
      const int g = kk * 4 + lg;
      f16x8 b0f[4], b1f[4];
      #pragma unroll
      for (int n = 0; n < 4; ++n) {
        const size_t off = (size_t)(g * 128 + wc + n * 16 + l15) * 16;
        b0f[n] = *(const f16x8*)(sB0 + off);
        if (SPLIT) b1f[n] = *(const f16x8*)(sB1 + off);
      }
      #pragma unroll
      for (int m = 0; m < 4; ++m) {
        const size_t ao = (size_t)(g * 128 + wr + m * 16 + l15) * 16;
        const f16x8 a0 = *(const f16x8*)(sA0 + ao);
        f16x8 a1;
        if (SPLIT) a1 = *(const f16x8*)(sA1 + ao);
        #pragma unroll
        for (int n = 0; n < 4; ++n) {
          if (SPLIT) {
            acc2[m][n] = __builtin_amdgcn_mfma_f32_16x16x32_f16(a1, b0f[n], acc2[m][n], 0, 0, 0);
            acc2[m][n] = __builtin_amdgcn_mfma_f32_16x16x32_f16(a0, b1f[n], acc2[m][n], 0, 0, 0);
          }
          acc[m][n] = __builtin_amdgcn_mfma_f32_16x16x32_f16(a0, b0f[n], acc[m][n], 0, 0, 0);
        }
      }
    }
    __syncthreads();
  }

  // epilogue. C/D mapping: col = lane&15, row = (lane>>4)*4 + j  [m89-verified]
  #pragma unroll
  for (int n = 0; n < 4; ++n) {
    const int cn = col0 + wc + n * 16 + l15;
    const float bv = bias[cn];
    #pragma unroll
    for (int m = 0; m < 4; ++m) {
      const int r0 = wr + m * 16 + ((lane >> 4) << 2);
      #pragma unroll
      for (int jj = 0; jj < 4; ++jj) {
        const int rm = tile0 + r0 + jj;
        if (EXPERT && rm >= Mloc) continue;
        float v = acc[m][n][jj];
        if (SPLIT) v += acc2[m][n][jj] * (1.f / 2048.f);
        v += bv;
        const size_t ci = (size_t)(EXPERT ? (rowBase + rm) : rm) * N + cn;
        if (EPI == 0) {
          const unsigned short h0 = f2h(v);
          Cb0[ci] = h0;
          Cb1[ci] = f2h((v - h2f(h0)) * 2048.f);
        } else if (EPI == 1) {
          Cb0[ci] = f2h(fmaxf(v, 0.f));
        } else if (EPI == 2) {
          Cb0[ci] = f2h(v * pairW[rowBase + rm]);
        } else if (EPI == 3) {
          Cf[ci] = v;
        } else {
          Cf[ci] = fmaxf(v, 0.f);
        }
      }
    }
  }
}

// ---------------------------------------------------------------------------
// transpose+convert: src fp32 [z][R][C] -> fp16 level arrays [z][C][R].
// LEV=2: level-1 stored x2048. TASK: src += (*taskPtr)*R*C (extract task t).
// ---------------------------------------------------------------------------
template<int LEV, int TASK>
__global__ __launch_bounds__(256)
void transp_k(const float* __restrict__ src, unsigned short* __restrict__ d0,
              unsigned short* __restrict__ d1, const int* __restrict__ taskPtr,
              int R, int C)
{
  __shared__ float tle[32][33];
  size_t bb = (size_t)blockIdx.z * R * C;
  if (TASK) bb = (size_t)(*taskPtr) * R * C;
  const int r0 = blockIdx.x * 32, c0 = blockIdx.y * 32;
  const int x = threadIdx.x & 31, y = threadIdx.x >> 5;
  #pragma unroll
  for (int i = 0; i < 32; i += 8)
    tle[y + i][x] = src[bb + (size_t)(r0 + y + i) * C + (c0 + x)];
  __syncthreads();
  const size_t db = TASK ? 0 : (size_t)blockIdx.z * R * C;
  #pragma unroll
  for (int i = 0; i < 32; i += 8) {
    const float v = tle[x][y + i];
    const size_t di = db + (size_t)(c0 + y + i) * R + (r0 + x);
    const unsigned short h0 = f2h(v);
    d0[di] = h0;
    if (LEV > 1) d1[di] = f2h((v - h2f(h0)) * 2048.f);
  }
}

// ---------------------------------------------------------------------------
// In-place LayerNorm (+ optional relu) over fp32 rows of COLS.
// ---------------------------------------------------------------------------
template<int COLS, bool RELU>
__global__ __launch_bounds__(256)
void ln_k(float* __restrict__ x, const float* __restrict__ g, const float* __restrict__ b)
{
  constexpr int PER = COLS / 256;
  const size_t row = blockIdx.x;
  float* xr = x + row * COLS;
  float v[PER];
  float s = 0.f, s2 = 0.f;
  #pragma unroll
  for (int i = 0; i < PER; ++i) {
    v[i] = xr[threadIdx.x + i * 256];
    s += v[i];
    s2 += v[i] * v[i];
  }
  #pragma unroll
  for (int o = 1; o < 64; o <<= 1) { s += __shfl_xor(s, o); s2 += __shfl_xor(s2, o); }
  __shared__ float ss[4], ss2[4];
  const int w = threadIdx.x >> 6;
  if ((threadIdx.x & 63) == 0) { ss[w] = s; ss2[w] = s2; }
  __syncthreads();
  s  = ss[0] + ss[1] + ss[2] + ss[3];
  s2 = ss2[0] + ss2[1] + ss2[2] + ss2[3];
  const float mu = s * (1.f / COLS);
  const float var = s2 * (1.f / COLS) - mu * mu;
  const float rs = rsqrtf(var + 1e-5f);
  #pragma unroll
  for (int i = 0; i < PER; ++i) {
    const int c = threadIdx.x + i * 256;
    float y = (v[i] - mu) * rs * g[c] + b[c];
    if (RELU) y = fmaxf(y, 0.f);
    xr[c] = y;
  }
}

// ---------------------------------------------------------------------------
// In-place LayerNorm (+ optional relu) over fp16 hi/lo pair rows (fp32 math).
// ---------------------------------------------------------------------------
template<int COLS, bool RELU>
__global__ __launch_bounds__(256)
void ln_pair_k(unsigned short* __restrict__ h0, unsigned short* __restrict__ h1,
               const float* __restrict__ g, const float* __restrict__ b)
{
  constexpr int PER = COLS / 256;
  const size_t row = blockIdx.x;
  unsigned short* r0 = h0 + row * COLS;
  unsigned short* r1 = h1 + row * COLS;
  const int c0 = threadIdx.x * PER;
  float v[PER];
  float s = 0.f, s2 = 0.f;
  #pragma unroll
  for (int i = 0; i < PER; i += 4) {
    const ushort4 a = *(const ushort4*)(r0 + c0 + i);
    const ushort4 c = *(const ushort4*)(r1 + c0 + i);
    v[i+0] = h2f(a.x) + h2f(c.x) * (1.f/2048.f);
    v[i+1] = h2f(a.y) + h2f(c.y) * (1.f/2048.f);
    v[i+2] = h2f(a.z) + h2f(c.z) * (1.f/2048.f);
    v[i+3] = h2f(a.w) + h2f(c.w) * (1.f/2048.f);
  }
  #pragma unroll
  for (int i = 0; i < PER; ++i) { s += v[i]; s2 += v[i] * v[i]; }
  #pragma unroll
  for (int o = 1; o < 64; o <<= 1) { s += __shfl_xor(s, o); s2 += __shfl_xor(s2, o); }
  __shared__ float ss[4], ss2[4];
  const int w = threadIdx.x >> 6;
  if ((threadIdx.x & 63) == 0) { ss[w] = s; ss2[w] = s2; }
  __syncthreads();
  s  = ss[0] + ss[1] + ss[2] + ss[3];
  s2 = ss2[0] + ss2[1] + ss2[2] + ss2[3];
  const float mu = s * (1.f / COLS);
  const float var = s2 * (1.f / COLS) - mu * mu;
  const float rs = rsqrtf(var + 1e-5f);
  #pragma unroll
  for (int i = 0; i < PER; i += 4) {
    ushort4 a4, c4v;
    unsigned short* ap = (unsigned short*)&a4;
    unsigned short* cp = (unsigned short*)&c4v;
    #pragma unroll
    for (int jq = 0; jq < 4; ++jq) {
      const int c = c0 + i + jq;
      float y = (v[i+jq] - mu) * rs * g[c] + b[c];
      if (RELU) y = fmaxf(y, 0.f);
      const unsigned short hh = f2h(y);
      ap[jq] = hh;
      cp[jq] = f2h((y - h2f(hh)) * 2048.f);
    }
    *(ushort4*)(r0 + c0 + i) = a4;
    *(ushort4*)(r1 + c0 + i) = c4v;
  }
}

// ---------------------------------------------------------------------------
// gate: logits = g @ gW2[t] + gb2[t]; top-3 softmax; NO global atomics.
// ---------------------------------------------------------------------------
__global__ __launch_bounds__(256)
void gate_topk_k(const float* __restrict__ g, const float* __restrict__ gW2,
                 const float* __restrict__ gb2, const int* __restrict__ taskPtr,
                 float* __restrict__ gatesOut, int* __restrict__ topkIdx,
                 float* __restrict__ topkW)
{
  const int t = *taskPtr;
  const float* W = gW2 + (size_t)t * 128 * 16;
  const float* bias = gb2 + (size_t)t * 16;
  const int lane = threadIdx.x & 63;
  const int row = blockIdx.x * 4 + (threadIdx.x >> 6);
  const float* gr = g + (size_t)row * 128;
  const int e = lane & 15;
  const int q = lane >> 4;
  float s = 0.f;
  for (int j = q * 32; j < q * 32 + 32; ++j) s = fmaf(gr[j], W[j * 16 + e], s);
  s += __shfl_xor(s, 16);
  s += __shfl_xor(s, 32);
  s += bias[e];
  float logits[16];
  #pragma unroll
  for (int i = 0; i < 16; ++i) logits[i] = __shfl(s, i);
  int i0 = 0; float v0 = logits[0];
  #pragma unroll
  for (int i = 1; i < 16; ++i) if (logits[i] > v0) { v0 = logits[i]; i0 = i; }
  int i1 = -1; float v1 = -3.4e38f;
  #pragma unroll
  for (int i = 0; i < 16; ++i) if (i != i0 && logits[i] > v1) { v1 = logits[i]; i1 = i; }
  int i2 = -1; float v2 = -3.4e38f;
  #pragma unroll
  for (int i = 0; i < 16; ++i) if (i != i0 && i != i1 && logits[i] > v2) { v2 = logits[i]; i2 = i; }
  const float ex1 = expf(v1 - v0);
  const float ex2 = expf(v2 - v0);
  const float inv = 1.f / (1.f + ex1 + ex2);
  const float p0 = inv, p1 = ex1 * inv, p2 = ex2 * inv;
  if (lane < 16) {
    const float gv = (lane == i0) ? p0 : (lane == i1) ? p1 : (lane == i2) ? p2 : 0.f;
    gatesOut[(size_t)row * 16 + lane] = gv;
  }
  if (lane == 0) {
    topkIdx[row * 3 + 0] = i0; topkIdx[row * 3 + 1] = i1; topkIdx[row * 3 + 2] = i2;
    topkW [row * 3 + 0] = p0; topkW [row * 3 + 1] = p1; topkW [row * 3 + 2] = p2;
  }
}

// per-chunk expert histogram (LDS atomics only)
__global__ __launch_bounds__(256)
void hist_k(const int* __restrict__ topkIdx, int* __restrict__ chunkCnt)
{
  __shared__ int lc[NEXP];
  if (threadIdx.x < NEXP) lc[threadIdx.x] = 0;
  __syncthreads();
  const int row = blockIdx.x * 256 + threadIdx.x;
  #pragma unroll
  for (int k = 0; k < 3; ++k) atomicAdd(&lc[topkIdx[row * 3 + k]], 1);
  __syncthreads();
  if (threadIdx.x < NEXP) chunkCnt[blockIdx.x * NEXP + threadIdx.x] = lc[threadIdx.x];
}

// serial scan: counts/offs per expert + per-chunk bases
__global__ void scanB_k(const int* __restrict__ chunkCnt, int* __restrict__ counts,
                        int* __restrict__ offs, int* __restrict__ chunkBase)
{
  if (threadIdx.x == 0) {
    int tot[NEXP];
    for (int e = 0; e < NEXP; ++e) tot[e] = 0;
    for (int c = 0; c < 64; ++c)
      for (int e = 0; e < NEXP; ++e) tot[e] += chunkCnt[c * NEXP + e];
    int a = 0;
    for (int e = 0; e < NEXP; ++e) { offs[e] = a; counts[e] = tot[e]; a += tot[e]; }
    for (int e = 0; e < NEXP; ++e) {
      int b = offs[e];
      for (int c = 0; c < 64; ++c) { chunkBase[c * NEXP + e] = b; b += chunkCnt[c * NEXP + e]; }
    }
  }
}

// fill pair lists: LDS-atomic within-chunk offsets + precomputed chunk base
__global__ __launch_bounds__(256)
void fill2_k(const int* __restrict__ topkIdx, const float* __restrict__ topkW,
             const int* __restrict__ chunkBase, int* __restrict__ pairRow,
             float* __restrict__ pairW, int* __restrict__ rowPos)
{
  __shared__ int lc[NEXP];
  if (threadIdx.x < NEXP) lc[threadIdx.x] = 0;
  __syncthreads();
  const int row = blockIdx.x * 256 + threadIdx.x;
  #pragma unroll
  for (int k = 0; k < 3; ++k) {
    const int e = topkIdx[row * 3 + k];
    const int lofs = atomicAdd(&lc[e], 1);
    const int pos = chunkBase[blockIdx.x * NEXP + e] + lofs;
    pairRow[pos] = row;
    pairW[pos] = topkW[row * 3 + k];
    rowPos[row * 3 + k] = pos;
  }
}

// mix (fp16 out) = sum of the row's 3 eo slots
__global__ __launch_bounds__(256)
void mixreduce_k(const unsigned short* __restrict__ eo, const int* __restrict__ rowPos,
                 unsigned short* __restrict__ mix16)
{
  const size_t row = blockIdx.x;
  const size_t p0 = rowPos[row * 3 + 0];
  const size_t p1 = rowPos[row * 3 + 1];
  const size_t p2 = rowPos[row * 3 + 2];
  for (int c = threadIdx.x; c < EXPSZ; c += 256) {
    mix16[row * EXPSZ + c] = f2h(h2f(eo[p0 * EXPSZ + c]) + h2f(eo[p1 * EXPSZ + c])
                               + h2f(eo[p2 * EXPSZ + c]));
  }
}

__global__ __launch_bounds__(256)
void tower3_k(const unsigned short* __restrict__ t2, const float* __restrict__ tW3,
              const float* __restrict__ tb3, const int* __restrict__ taskPtr,
              float* __restrict__ out)
{
  const int t = *taskPtr;
  const float* w = tW3 + (size_t)t * 128;
  const float bias = tb3[t];
  const int lane = threadIdx.x & 63;
  const int row = blockIdx.x * 4 + (threadIdx.x >> 6);
  const unsigned short* x = t2 + (size_t)row * 128;
  float s = fmaf(h2f(x[lane]), w[lane], h2f(x[lane + 64]) * w[lane + 64]);
  #pragma unroll
  for (int o = 1; o < 64; o <<= 1) s += __shfl_xor(s, o);
  if (lane == 0) out[row] = 1.f / (1.f + expf(-(s + bias)));
  if (blockIdx.x == 0 && threadIdx.x == 0) out[BATCH] = (float)t;
}

// ---------------------------------------------------------------------------
extern "C" void kernel_launch(void* const* d_in, const int* in_sizes, int n_in,
                              void* d_out, int out_size, void* d_ws, size_t ws_size,
                              hipStream_t stream)
{
  (void)in_sizes; (void)n_in; (void)out_size; (void)ws_size;
  const float* embP  = (const float*)d_in[0];
  const float* embR  = (const float*)d_in[1];
  const float* encW1 = (const float*)d_in[2];
  const float* encB1 = (const float*)d_in[3];
  const float* ln1g  = (const float*)d_in[4];
  const float* ln1b  = (const float*)d_in[5];
  const float* encW2 = (const float*)d_in[6];
  const float* encB2 = (const float*)d_in[7];
  const float* ln2g  = (const float*)d_in[8];
  const float* ln2b  = (const float*)d_in[9];
  const float* gW1   = (const float*)d_in[10];
  const float* gb1   = (const float*)d_in[11];
  const float* gW2   = (const float*)d_in[12];
  const float* gb2   = (const float*)d_in[13];
  const float* We1   = (const float*)d_in[14];
  const float* be1   = (const float*)d_in[15];
  const float* We2   = (const float*)d_in[16];
  const float* be2   = (const float*)d_in[17];
  const float* tW1   = (const float*)d_in[18];
  const float* tb1   = (const float*)d_in[19];
  const float* tW2   = (const float*)d_in[20];
  const float* tb2   = (const float*)d_in[21];
  const float* tW3   = (const float*)d_in[22];
  const float* tb3   = (const float*)d_in[23];
  const int* taskPtr = (const int*)d_in[24];

  float* out = (float*)d_out;
  char* ws = (char*)d_ws;
  const size_t MB = 1ull << 20;

  // Lifetime-aliased workspace (peak ~209 MB):
  //  [0,64):   feat0[0,32),feat1[32,64)
  //            feat1 dead after gate -> mix16[32,48), t1f16[48,56), t2f16[56,60)
  //  [64,192): h fp32[64,192) -> We1t0[64,80),We2t0[80,88),
  //            e1b[88,136), eob[136,184)
  //  [192,208): W1t0[192,196),W1t1[196,200) -> gbuf[192,200) -> tW1t,tW2t
  //             W2t0[200,204),W2t1[204,208) -> gW1t0[200,204),gW1t1[204,208)
  //  [208,~209): metadata
  unsigned short* feat0 = (unsigned short*)(ws);
  unsigned short* feat1 = (unsigned short*)(ws + 32 * MB);
  unsigned short* mix16 = (unsigned short*)(ws + 32 * MB);
  unsigned short* t1f16 = (unsigned short*)(ws + 48 * MB);
  unsigned short* t2f16 = (unsigned short*)(ws + 56 * MB);
  float* h = (float*)(ws + 64 * MB);
  unsigned short* We1t0 = (unsigned short*)(ws + 64 * MB);
  unsigned short* We2t0 = (unsigned short*)(ws + 80 * MB);
  unsigned short* e1b   = (unsigned short*)(ws + 88 * MB);
  unsigned short* eob   = (unsigned short*)(ws + 136 * MB);
  unsigned short* W1t0  = (unsigned short*)(ws + 192 * MB);
  unsigned short* W1t1  = (unsigned short*)(ws + 196 * MB);
  unsigned short* W2t0  = (unsigned short*)(ws + 200 * MB);
  unsigned short* W2t1  = (unsigned short*)(ws + 204 * MB);
  unsigned short* gW1t0 = (unsigned short*)(ws + 200 * MB);
  unsigned short* gW1t1 = (unsigned short*)(ws + 204 * MB);
  float* gbuf = (float*)(ws + 192 * MB);
  unsigned short* tW1t = (unsigned short*)(ws + 192 * MB);
  unsigned short* tW2t = (unsigned short*)(ws + 193 * MB);
  char* small = ws + 208 * MB;
  int*   counts    = (int*)  (small);
  int*   offs      = (int*)  (small + 1024);
  int*   chunkCnt  = (int*)  (small + 2048);
  int*   chunkBase = (int*)  (small + 2048 + 4096);
  int*   topkIdx   = (int*)  (small + 16384);
  float* topkW     = (float*)(small + 16384 + 196608);
  int*   pairRow   = (int*)  (small + 16384 + 2 * 196608);
  float* pairW     = (float*)(small + 16384 + 3 * 196608);
  int*   rowPos    = (int*)  (small + 16384 + 4 * 196608);

  const dim3 blk(256, 1, 1);

  // encoder GEMM1: h = concat(embP,embR) @ W1 + b1 (reg-staged fp32 A, BK=32)
  transp_k<2,0><<<dim3(DIN/32, DHID/32, 1), blk, 0, stream>>>(encW1, W1t0, W1t1, nullptr, DIN, DHID);
  mgemm_k<1,1,3,3,32,DHID/128,0><<<dim3((BATCH/128)*(DHID/128), 1, 1), blk, 0, stream>>>(
      nullptr, nullptr, embP, embR, W1t0, W1t1, encB1, h, nullptr, nullptr,
      nullptr, nullptr, nullptr, nullptr, nullptr, BATCH, DHID, DIN);
  ln_k<DHID, true><<<dim3(BATCH, 1, 1), blk, 0, stream>>>(h, ln1g, ln1b);

  // encoder GEMM2: feat = h @ W2 + b2 (reg-staged fp32 A, BK=32) -> fp16 pair
  transp_k<2,0><<<dim3(DHID/32, DIN/32, 1), blk, 0, stream>>>(encW2, W2t0, W2t1, nullptr, DHID, DIN);
  mgemm_k<1,1,0,0,32,DIN/128,0><<<dim3((BATCH/128)*(DIN/128), 1, 1), blk, 0, stream>>>(
      nullptr, nullptr, h, nullptr, W2t0, W2t1, encB2, nullptr, feat0, feat1,
      nullptr, nullptr, nullptr, nullptr, nullptr, BATCH, DIN, DHID);
  ln_pair_k<DIN, false><<<dim3(BATCH, 1, 1), blk, 0, stream>>>(feat0, feat1, ln2g, ln2b);

  // gate: g = relu(feat @ gW1[t] + gb1[t])  (fp16 split MFMA -> fp32 gbuf)
  transp_k<2,1><<<dim3(DIN/32, 128/32, 1), blk, 0, stream>>>(gW1, gW1t0, gW1t1, taskPtr, DIN, 128);
  mgemm_k<1,0,0,4,64,1,1><<<dim3(BATCH/128, 1, 1), blk, 0, stream>>>(
      feat0, feat1, nullptr, nullptr, gW1t0, gW1t1, gb1, gbuf, nullptr, nullptr,
      nullptr, nullptr, nullptr, nullptr, taskPtr, BATCH, 128, DIN);
  gate_topk_k<<<dim3(BATCH/4, 1, 1), blk, 0, stream>>>(
      gbuf, gW2, gb2, taskPtr, out + BATCH + 1, topkIdx, topkW);
  hist_k<<<dim3(BATCH/256, 1, 1), blk, 0, stream>>>(topkIdx, chunkCnt);
  scanB_k<<<dim3(1, 1, 1), dim3(64, 1, 1), 0, stream>>>(chunkCnt, counts, offs, chunkBase);
  fill2_k<<<dim3(BATCH/256, 1, 1), blk, 0, stream>>>(topkIdx, topkW, chunkBase,
                                                     pairRow, pairW, rowPos);

  // expert weights in fp16 (h region free now)
  transp_k<1,0><<<dim3(DIN/32, EXPSZ/32, NEXP), blk, 0, stream>>>(We1, We1t0, nullptr, nullptr, DIN, EXPSZ);
  transp_k<1,0><<<dim3(EXPSZ/32, EXPSZ/32, NEXP), blk, 0, stream>>>(We2, We2t0, nullptr, nullptr, EXPSZ, EXPSZ);

  // expert GEMM1: e1 = relu(feat0[pairRow] @ We1[e] + be1)  (plain fp16)
  mgemm_k<0,0,1,1,64,EXPSZ/128,0><<<dim3((BATCH/128)*(EXPSZ/128), 1, NEXP), blk, 0, stream>>>(
      feat0, nullptr, nullptr, nullptr, We1t0, nullptr, be1, nullptr, e1b, nullptr,
      pairRow, nullptr, counts, offs, nullptr, NPAIR, EXPSZ, DIN);
  // expert GEMM2: eo = w_p * (e1 @ We2[e] + be2)  (plain fp16)
  mgemm_k<0,0,2,2,64,EXPSZ/128,0><<<dim3((BATCH/128)*(EXPSZ/128), 1, NEXP), blk, 0, stream>>>(
      e1b, nullptr, nullptr, nullptr, We2t0, nullptr, be2, nullptr, eob, nullptr,
      nullptr, pairW, counts, offs, nullptr, NPAIR, EXPSZ, EXPSZ);
  mixreduce_k<<<dim3(BATCH, 1, 1), blk, 0, stream>>>(eob, rowPos, mix16);

  // towers (plain fp16 MFMA, task-indexed weights/bias)
  transp_k<1,1><<<dim3(EXPSZ/32, 256/32, 1), blk, 0, stream>>>(tW1, tW1t, nullptr, taskPtr, EXPSZ, 256);
  transp_k<1,1><<<dim3(256/32, 128/32, 1), blk, 0, stream>>>(tW2, tW2t, nullptr, taskPtr, 256, 128);
  mgemm_k<0,0,0,1,64,2,1><<<dim3((BATCH/128)*2, 1, 1), blk, 0, stream>>>(
      mix16, nullptr, nullptr, nullptr, tW1t, nullptr, tb1, nullptr, t1f16, nullptr,
      nullptr, nullptr, nullptr, nullptr, taskPtr, BATCH, 256, EXPSZ);
  mgemm_k<0,0,0,1,64,1,1><<<dim3(BATCH/128, 1, 1), blk, 0, stream>>>(
      t1f16, nullptr, nullptr, nullptr, tW2t, nullptr, tb2, nullptr, t2f16, nullptr,
      nullptr, nullptr, nullptr, nullptr, taskPtr, BATCH, 128, 256);
  tower3_k<<<dim3(BATCH/4, 1, 1), blk, 0, stream>>>(t2f16, tW3, tb3, taskPtr, out);
}

// Round 15
// 1054.903 us; speedup vs baseline: 1.7196x; 1.0526x over previous
//
#include <hip/hip_runtime.h>

typedef __attribute__((ext_vector_type(8))) _Float16 f16x8;
typedef __attribute__((ext_vector_type(4))) float f32x4;

#define DEVINL __device__ __forceinline__

constexpr int BATCH = 16384;
constexpr int DIN   = 1024;
constexpr int DHID  = 2048;
constexpr int NEXP  = 16;
constexpr int EXPSZ = 512;
constexpr int NPAIR = BATCH * 3;

DEVINL unsigned short f2h(float v) {
  _Float16 h = (_Float16)v;
  return __builtin_bit_cast(unsigned short, h);
}
DEVINL float h2f(unsigned short u) {
  return (float)__builtin_bit_cast(_Float16, u);
}

DEVINL void gl2lds(const unsigned short* src, char* ldst) {
  __builtin_amdgcn_global_load_lds((const __attribute__((address_space(1))) void*)src,
                                   (__attribute__((address_space(3))) void*)ldst, 16, 0, 0);
}

// ---------------------------------------------------------------------------
// fp16 split-MFMA GEMM, 128x128 tile, 4 waves (2x2 of 64x64), 16x16x32 f16.
// r15: 2-PHASE DOUBLE-BUFFERED pipeline (T3 minimum recipe + T14 write-late).
//   prologue: full-stage tile0 into buf0; barrier.
//   iter t: ISSUE tile t+1 loads (B gl2lds into buf^1; A fp32 -> regs),
//           COMPUTE tile t from buf (ds_read+MFMA),
//           WRITE-LATE A (convert regs -> ds_write buf^1),
//           one barrier; swap.  Loads for t+1 stay in flight across the
//   whole MFMA phase instead of being serially drained pre-compute
//   (the m97-structure stall: MfmaUtil 24%, VALU 17% at 2 blocks/CU).
// B staged via global_load_lds from fp16 level arrays Bt[N][K].
// ASTAGE: 0 = A fp16 level arrays via gl2lds; 1 = A fp32 reg-staged
//   (r14: beats pre-materialized pair; conversion VALU off critical path).
// 1D grid (x = NXT*NYT, z = expert); row-tiles round-robined over XCDs,
// col-tiles consecutive within an XCD (r10; bijective for NXT%8==0).
// OCCUPANCY (r11): SPLIT kernels stay at 2 blocks/CU (3 -> L2 overflow,
// WRITE 208MB->1GB). BK=32 everywhere (r13: BK=64 lost L2 reuse); dbuf
// LDS: enc/gate 64KB@2, experts/towers 32KB@3 — all fit 160KB.
// SPLIT=1: v = c0 + c1/2048 (c1 stored x2048). 3 MFMA terms. SPLIT=0: fp16.
// AMODE: 0 linear A rows; 1 gather via pairRow; 2 pair-linear;
//        3 concat(embP,embR) fp32 rows (requires ASTAGE=1).
// TASK:  bias += (*taskPtr)*N.
// EPI:   0 +bias -> fp16 hi/lo pair; 1 +bias,relu -> fp16;
//        2 +bias,*pairW -> fp16; 3 +bias -> fp32; 4 +bias,relu -> fp32.
// ---------------------------------------------------------------------------
template<int SPLIT, int ASTAGE, int AMODE, int EPI, int BK, int NYT, int TASK>
__global__ __launch_bounds__(256, SPLIT ? 2 : 3)
void mgemm_k(const unsigned short* __restrict__ A0p,
             const unsigned short* __restrict__ A1p,
             const float* __restrict__ Af0, const float* __restrict__ Af1,
             const unsigned short* __restrict__ B0p,
             const unsigned short* __restrict__ B1p,
             const float* __restrict__ biasb,
             float* __restrict__ Cf, unsigned short* __restrict__ Cb0,
             unsigned short* __restrict__ Cb1,
             const int* __restrict__ pairRow, const float* __restrict__ pairW,
             const int* __restrict__ counts, const int* __restrict__ offs,
             const int* __restrict__ taskPtr,
             int M, int N, int K)
{
  constexpr int KG = BK / 8;
  constexpr int UNITS = 128 * KG;
  constexpr int ISS = UNITS / 256;
  constexpr int NKK = BK / 32;
  constexpr int NARR = SPLIT ? 4 : 2;
  constexpr size_t BUFSZ = (size_t)NARR * UNITS * 16;
  constexpr bool EXPERT = (AMODE == 1 || AMODE == 2);
  __shared__ char smem[2 * NARR * UNITS * 16];

  int Mloc = M, rowBase = 0;
  const unsigned short* b0 = B0p;
  const unsigned short* b1 = B1p;
  const float* bias = biasb;
  if (EXPERT) {
    const int e = blockIdx.z;
    Mloc = counts[e];
    rowBase = offs[e];
    const size_t eo = (size_t)e * (size_t)K * N;
    b0 = B0p + eo;
    if (SPLIT) b1 = B1p + eo;
    bias = biasb + (size_t)e * N;
  }
  if (TASK) bias = biasb + (size_t)(*taskPtr) * N;

  // round-robin row-tiles over XCDs; col-tiles consecutive within XCD
  const int xcd = (int)blockIdx.x & 7;
  const int j   = (int)blockIdx.x >> 3;
  const int tile0 = (xcd + 8 * (j / NYT)) * 128;
  const int col0  = (j % NYT) * 128;
  if (tile0 >= Mloc) return;

  const int tid = threadIdx.x;
  const int lane = tid & 63;
  const int wr = ((tid >> 6) >> 1) * 64;
  const int wc = ((tid >> 6) & 1) * 64;
  const int l15 = lane & 15;
  const int lg = lane >> 4;

  // per-thread staging row (fixed across K)
  const int srow = tid & 127;
  size_t aoff = 0;
  const float* aF = nullptr;
  const float* aP = nullptr;
  const float* aR = nullptr;
  if (ASTAGE) {
    if (AMODE == 3) {
      aP = Af0 + (size_t)(tile0 + srow) * 512;
      aR = Af1 + (size_t)(tile0 + srow) * 512;
    } else {
      aF = Af0 + (size_t)(tile0 + srow) * K;
    }
  } else if (AMODE == 0) {
    aoff = (size_t)(tile0 + srow) * K;
  } else if (AMODE == 1) {
    int p = rowBase + tile0 + srow; p = p < NPAIR - 1 ? p : NPAIR - 1;
    aoff = (size_t)pairRow[p] * K;
  } else {
    int p = rowBase + tile0 + srow; p = p < NPAIR - 1 ? p : NPAIR - 1;
    aoff = (size_t)p * K;
  }
  const size_t boff = (size_t)(col0 + srow) * K;

  f32x4 acc[4][4];
  f32x4 acc2[4][4];
  #pragma unroll
  for (int m = 0; m < 4; ++m)
    #pragma unroll
    for (int n = 0; n < 4; ++n) {
      acc[m][n] = f32x4{0.f, 0.f, 0.f, 0.f};
      if (SPLIT) acc2[m][n] = f32x4{0.f, 0.f, 0.f, 0.f};
    }

  // ---- prologue: full-stage tile 0 into buffer 0 ----
  {
    char* dA0 = smem;
    char* dA1 = smem + UNITS * 16;
    char* dB0 = smem + (SPLIT ? 2 : 1) * UNITS * 16;
    char* dB1 = smem + 3 * (size_t)UNITS * 16;
    if (ASTAGE) {
      #pragma unroll
      for (int it = 0; it < ISS; ++it) {
        const int u = it * 256 + tid;
        const int ko = (u >> 7) * 8;
        const float* s;
        if (AMODE == 3) s = (ko < 512) ? (aP + ko) : (aR + (ko - 512));
        else            s = aF + ko;
        const float4 x0 = *(const float4*)s;
        const float4 x1 = *(const float4*)(s + 4);
        const float vv[8] = {x0.x, x0.y, x0.z, x0.w, x1.x, x1.y, x1.z, x1.w};
        f16x8 q0, q1;
        #pragma unroll
        for (int jq = 0; jq < 8; ++jq) {
          const _Float16 c0 = (_Float16)vv[jq];
          q0[jq] = c0;
          if (SPLIT) q1[jq] = (_Float16)((vv[jq] - (float)c0) * 2048.f);
        }
        *(f16x8*)(dA0 + (size_t)u * 16) = q0;
        if (SPLIT) *(f16x8*)(dA1 + (size_t)u * 16) = q1;
      }
    }
    #pragma unroll
    for (int it = 0; it < ISS; ++it) {
      const int uo = (it * 256 + (tid & 192)) * 16;
      const int ko = (it * 2 + (tid >> 7)) * 8;
      if (!ASTAGE) {
        gl2lds(A0p + aoff + ko, dA0 + uo);
        if (SPLIT) gl2lds(A1p + aoff + ko, dA1 + uo);
      }
      gl2lds(b0 + boff + ko, dB0 + uo);
      if (SPLIT) gl2lds(b1 + boff + ko, dB1 + uo);
    }
  }
  __syncthreads();

  const int NT = K / BK;
  int cur = 0;
  for (int t = 0; t < NT; ++t) {
    const int nxt = cur ^ 1;
    const int ktn = (t + 1) * BK;
    const bool hav = (t + 1 < NT);
    char* nA0 = smem + (size_t)nxt * BUFSZ;
    char* nA1 = nA0 + UNITS * 16;
    char* nB0 = nA0 + (SPLIT ? 2 : 1) * UNITS * 16;
    char* nB1 = nA0 + 3 * (size_t)UNITS * 16;

    // ---- issue next-tile loads (stay in flight across the MFMA phase) ----
    float4 pf0[ISS], pf1[ISS];
    if (hav) {
      if (ASTAGE) {
        #pragma unroll
        for (int it = 0; it < ISS; ++it) {
          const int u = it * 256 + tid;
          const int ko = ktn + (u >> 7) * 8;
          const float* s;
          if (AMODE == 3) s = (ko < 512) ? (aP + ko) : (aR + (ko - 512));
          else            s = aF + ko;
          pf0[it] = *(const float4*)s;
          pf1[it] = *(const float4*)(s + 4);
        }
      } else {
        #pragma unroll
        for (int it = 0; it < ISS; ++it) {
          const int uo = (it * 256 + (tid & 192)) * 16;
          const int ko = ktn + (it * 2 + (tid >> 7)) * 8;
          gl2lds(A0p + aoff + ko, nA0 + uo);
          if (SPLIT) gl2lds(A1p + aoff + ko, nA1 + uo);
        }
      }
      #pragma unroll
      for (int it = 0; it < ISS; ++it) {
        const int uo = (it * 256 + (tid & 192)) * 16;
        const int ko = ktn + (it * 2 + (tid >> 7)) * 8;
        gl2lds(b0 + boff + ko, nB0 + uo);
        if (SPLIT) gl2lds(b1 + boff + ko, nB1 + uo);
      }
    }

    // ---- compute current tile ----
    {
      char* cA0 = smem + (size_t)cur * BUFSZ;
      char* cA1 = cA0 + UNITS * 16;
      char* cB0 = cA0 + (SPLIT ? 2 : 1) * UNITS * 16;
      char* cB1 = cA0 + 3 * (size_t)UNITS * 16;
      #pragma unroll
      for (int kk = 0; kk < NKK; ++kk) {
        const int g = kk * 4 + lg;
        f16x8 b0f[4], b1f[4];
        #pragma unroll
        for (int n = 0; n < 4; ++n) {
          const size_t off = (size_t)(g * 128 + wc + n * 16 + l15) * 16;
          b0f[n] = *(const f16x8*)(cB0 + off);
          if (SPLIT) b1f[n] = *(const f16x8*)(cB1 + off);
        }
        #pragma unroll
        for (int m = 0; m < 4; ++m) {
          const size_t ao = (size_t)(g * 128 + wr + m * 16 + l15) * 16;
          const f16x8 a0 = *(const f16x8*)(cA0 + ao);
          f16x8 a1;
          if (SPLIT) a1 = *(const f16x8*)(cA1 + ao);
          #pragma unroll
          for (int n = 0; n < 4; ++n) {
            if (SPLIT) {
              acc2[m][n] = __builtin_amdgcn_mfma_f32_16x16x32_f16(a1, b0f[n], acc2[m][n], 0, 0, 0);
              acc2[m][n] = __builtin_amdgcn_mfma_f32_16x16x32_f16(a0, b1f[n], acc2[m][n], 0, 0, 0);
            }
            acc[m][n] = __builtin_amdgcn_mfma_f32_16x16x32_f16(a0, b0f[n], acc[m][n], 0, 0, 0);
          }
        }
      }
    }

    // ---- write-late: convert prefetched A and ds_write into next buffer ----
    if (hav && ASTAGE) {
      #pragma unroll
      for (int it = 0; it < ISS; ++it) {
        const int u = it * 256 + tid;
        const float vv[8] = {pf0[it].x, pf0[it].y, pf0[it].z, pf0[it].w,
                             pf1[it].x, pf1[it].y, pf1[it].z, pf1[it].w};
        f16x8 q0, q1;
        #pragma unroll
        for (int jq = 0; jq < 8; ++jq) {
          const _Float16 c0 = (_Float16)vv[jq];
          q0[jq] = c0;
          if (SPLIT) q1[jq] = (_Float16)((vv[jq] - (float)c0) * 2048.f);
        }
        *(f16x8*)(nA0 + (size_t)u * 16) = q0;
        if (SPLIT) *(f16x8*)(nA1 + (size_t)u * 16) = q1;
      }
    }
    __syncthreads();
    cur = nxt;
  }

  // epilogue. C/D mapping: col = lane&15, row = (lane>>4)*4 + j  [m89-verified]
  #pragma unroll
  for (int n = 0; n < 4; ++n) {
    const int cn = col0 + wc + n * 16 + l15;
    const float bv = bias[cn];
    #pragma unroll
    for (int m = 0; m < 4; ++m) {
      const int r0 = wr + m * 16 + ((lane >> 4) << 2);
      #pragma unroll
      for (int jj = 0; jj < 4; ++jj) {
        const int rm = tile0 + r0 + jj;
        if (EXPERT && rm >= Mloc) continue;
        float v = acc[m][n][jj];
        if (SPLIT) v += acc2[m][n][jj] * (1.f / 2048.f);
        v += bv;
        const size_t ci = (size_t)(EXPERT ? (rowBase + rm) : rm) * N + cn;
        if (EPI == 0) {
          const unsigned short h0 = f2h(v);
          Cb0[ci] = h0;
          Cb1[ci] = f2h((v - h2f(h0)) * 2048.f);
        } else if (EPI == 1) {
          Cb0[ci] = f2h(fmaxf(v, 0.f));
        } else if (EPI == 2) {
          Cb0[ci] = f2h(v * pairW[rowBase + rm]);
        } else if (EPI == 3) {
          Cf[ci] = v;
        } else {
          Cf[ci] = fmaxf(v, 0.f);
        }
      }
    }
  }
}

// ---------------------------------------------------------------------------
// transpose+convert: src fp32 [z][R][C] -> fp16 level arrays [z][C][R].
// LEV=2: level-1 stored x2048. TASK: src += (*taskPtr)*R*C (extract task t).
// ---------------------------------------------------------------------------
template<int LEV, int TASK>
__global__ __launch_bounds__(256)
void transp_k(const float* __restrict__ src, unsigned short* __restrict__ d0,
              unsigned short* __restrict__ d1, const int* __restrict__ taskPtr,
              int R, int C)
{
  __shared__ float tle[32][33];
  size_t bb = (size_t)blockIdx.z * R * C;
  if (TASK) bb = (size_t)(*taskPtr) * R * C;
  const int r0 = blockIdx.x * 32, c0 = blockIdx.y * 32;
  const int x = threadIdx.x & 31, y = threadIdx.x >> 5;
  #pragma unroll
  for (int i = 0; i < 32; i += 8)
    tle[y + i][x] = src[bb + (size_t)(r0 + y + i) * C + (c0 + x)];
  __syncthreads();
  const size_t db = TASK ? 0 : (size_t)blockIdx.z * R * C;
  #pragma unroll
  for (int i = 0; i < 32; i += 8) {
    const float v = tle[x][y + i];
    const size_t di = db + (size_t)(c0 + y + i) * R + (r0 + x);
    const unsigned short h0 = f2h(v);
    d0[di] = h0;
    if (LEV > 1) d1[di] = f2h((v - h2f(h0)) * 2048.f);
  }
}

// ---------------------------------------------------------------------------
// In-place LayerNorm (+ optional relu) over fp32 rows of COLS.
// ---------------------------------------------------------------------------
template<int COLS, bool RELU>
__global__ __launch_bounds__(256)
void ln_k(float* __restrict__ x, const float* __restrict__ g, const float* __restrict__ b)
{
  constexpr int PER = COLS / 256;
  const size_t row = blockIdx.x;
  float* xr = x + row * COLS;
  float v[PER];
  float s = 0.f, s2 = 0.f;
  #pragma unroll
  for (int i = 0; i < PER; ++i) {
    v[i] = xr[threadIdx.x + i * 256];
    s += v[i];
    s2 += v[i] * v[i];
  }
  #pragma unroll
  for (int o = 1; o < 64; o <<= 1) { s += __shfl_xor(s, o); s2 += __shfl_xor(s2, o); }
  __shared__ float ss[4], ss2[4];
  const int w = threadIdx.x >> 6;
  if ((threadIdx.x & 63) == 0) { ss[w] = s; ss2[w] = s2; }
  __syncthreads();
  s  = ss[0] + ss[1] + ss[2] + ss[3];
  s2 = ss2[0] + ss2[1] + ss2[2] + ss2[3];
  const float mu = s * (1.f / COLS);
  const float var = s2 * (1.f / COLS) - mu * mu;
  const float rs = rsqrtf(var + 1e-5f);
  #pragma unroll
  for (int i = 0; i < PER; ++i) {
    const int c = threadIdx.x + i * 256;
    float y = (v[i] - mu) * rs * g[c] + b[c];
    if (RELU) y = fmaxf(y, 0.f);
    xr[c] = y;
  }
}

// ---------------------------------------------------------------------------
// In-place LayerNorm (+ optional relu) over fp16 hi/lo pair rows (fp32 math).
// ---------------------------------------------------------------------------
template<int COLS, bool RELU>
__global__ __launch_bounds__(256)
void ln_pair_k(unsigned short* __restrict__ h0, unsigned short* __restrict__ h1,
               const float* __restrict__ g, const float* __restrict__ b)
{
  constexpr int PER = COLS / 256;
  const size_t row = blockIdx.x;
  unsigned short* r0 = h0 + row * COLS;
  unsigned short* r1 = h1 + row * COLS;
  const int c0 = threadIdx.x * PER;
  float v[PER];
  float s = 0.f, s2 = 0.f;
  #pragma unroll
  for (int i = 0; i < PER; i += 4) {
    const ushort4 a = *(const ushort4*)(r0 + c0 + i);
    const ushort4 c = *(const ushort4*)(r1 + c0 + i);
    v[i+0] = h2f(a.x) + h2f(c.x) * (1.f/2048.f);
    v[i+1] = h2f(a.y) + h2f(c.y) * (1.f/2048.f);
    v[i+2] = h2f(a.z) + h2f(c.z) * (1.f/2048.f);
    v[i+3] = h2f(a.w) + h2f(c.w) * (1.f/2048.f);
  }
  #pragma unroll
  for (int i = 0; i < PER; ++i) { s += v[i]; s2 += v[i] * v[i]; }
  #pragma unroll
  for (int o = 1; o < 64; o <<= 1) { s += __shfl_xor(s, o); s2 += __shfl_xor(s2, o); }
  __shared__ float ss[4], ss2[4];
  const int w = threadIdx.x >> 6;
  if ((threadIdx.x & 63) == 0) { ss[w] = s; ss2[w] = s2; }
  __syncthreads();
  s  = ss[0] + ss[1] + ss[2] + ss[3];
  s2 = ss2[0] + ss2[1] + ss2[2] + ss2[3];
  const float mu = s * (1.f / COLS);
  const float var = s2 * (1.f / COLS) - mu * mu;
  const float rs = rsqrtf(var + 1e-5f);
  #pragma unroll
  for (int i = 0; i < PER; i += 4) {
    ushort4 a4, c4v;
    unsigned short* ap = (unsigned short*)&a4;
    unsigned short* cp = (unsigned short*)&c4v;
    #pragma unroll
    for (int jq = 0; jq < 4; ++jq) {
      const int c = c0 + i + jq;
      float y = (v[i+jq] - mu) * rs * g[c] + b[c];
      if (RELU) y = fmaxf(y, 0.f);
      const unsigned short hh = f2h(y);
      ap[jq] = hh;
      cp[jq] = f2h((y - h2f(hh)) * 2048.f);
    }
    *(ushort4*)(r0 + c0 + i) = a4;
    *(ushort4*)(r1 + c0 + i) = c4v;
  }
}

// ---------------------------------------------------------------------------
// gate: logits = g @ gW2[t] + gb2[t]; top-3 softmax; NO global atomics.
// ---------------------------------------------------------------------------
__global__ __launch_bounds__(256)
void gate_topk_k(const float* __restrict__ g, const float* __restrict__ gW2,
                 const float* __restrict__ gb2, const int* __restrict__ taskPtr,
                 float* __restrict__ gatesOut, int* __restrict__ topkIdx,
                 float* __restrict__ topkW)
{
  const int t = *taskPtr;
  const float* W = gW2 + (size_t)t * 128 * 16;
  const float* bias = gb2 + (size_t)t * 16;
  const int lane = threadIdx.x & 63;
  const int row = blockIdx.x * 4 + (threadIdx.x >> 6);
  const float* gr = g + (size_t)row * 128;
  const int e = lane & 15;
  const int q = lane >> 4;
  float s = 0.f;
  for (int j = q * 32; j < q * 32 + 32; ++j) s = fmaf(gr[j], W[j * 16 + e], s);
  s += __shfl_xor(s, 16);
  s += __shfl_xor(s, 32);
  s += bias[e];
  float logits[16];
  #pragma unroll
  for (int i = 0; i < 16; ++i) logits[i] = __shfl(s, i);
  int i0 = 0; float v0 = logits[0];
  #pragma unroll
  for (int i = 1; i < 16; ++i) if (logits[i] > v0) { v0 = logits[i]; i0 = i; }
  int i1 = -1; float v1 = -3.4e38f;
  #pragma unroll
  for (int i = 0; i < 16; ++i) if (i != i0 && logits[i] > v1) { v1 = logits[i]; i1 = i; }
  int i2 = -1; float v2 = -3.4e38f;
  #pragma unroll
  for (int i = 0; i < 16; ++i) if (i != i0 && i != i1 && logits[i] > v2) { v2 = logits[i]; i2 = i; }
  const float ex1 = expf(v1 - v0);
  const float ex2 = expf(v2 - v0);
  const float inv = 1.f / (1.f + ex1 + ex2);
  const float p0 = inv, p1 = ex1 * inv, p2 = ex2 * inv;
  if (lane < 16) {
    const float gv = (lane == i0) ? p0 : (lane == i1) ? p1 : (lane == i2) ? p2 : 0.f;
    gatesOut[(size_t)row * 16 + lane] = gv;
  }
  if (lane == 0) {
    topkIdx[row * 3 + 0] = i0; topkIdx[row * 3 + 1] = i1; topkIdx[row * 3 + 2] = i2;
    topkW [row * 3 + 0] = p0; topkW [row * 3 + 1] = p1; topkW [row * 3 + 2] = p2;
  }
}

// per-chunk expert histogram (LDS atomics only)
__global__ __launch_bounds__(256)
void hist_k(const int* __restrict__ topkIdx, int* __restrict__ chunkCnt)
{
  __shared__ int lc[NEXP];
  if (threadIdx.x < NEXP) lc[threadIdx.x] = 0;
  __syncthreads();
  const int row = blockIdx.x * 256 + threadIdx.x;
  #pragma unroll
  for (int k = 0; k < 3; ++k) atomicAdd(&lc[topkIdx[row * 3 + k]], 1);
  __syncthreads();
  if (threadIdx.x < NEXP) chunkCnt[blockIdx.x * NEXP + threadIdx.x] = lc[threadIdx.x];
}

// serial scan: counts/offs per expert + per-chunk bases
__global__ void scanB_k(const int* __restrict__ chunkCnt, int* __restrict__ counts,
                        int* __restrict__ offs, int* __restrict__ chunkBase)
{
  if (threadIdx.x == 0) {
    int tot[NEXP];
    for (int e = 0; e < NEXP; ++e) tot[e] = 0;
    for (int c = 0; c < 64; ++c)
      for (int e = 0; e < NEXP; ++e) tot[e] += chunkCnt[c * NEXP + e];
    int a = 0;
    for (int e = 0; e < NEXP; ++e) { offs[e] = a; counts[e] = tot[e]; a += tot[e]; }
    for (int e = 0; e < NEXP; ++e) {
      int b = offs[e];
      for (int c = 0; c < 64; ++c) { chunkBase[c * NEXP + e] = b; b += chunkCnt[c * NEXP + e]; }
    }
  }
}

// fill pair lists: LDS-atomic within-chunk offsets + precomputed chunk base
__global__ __launch_bounds__(256)
void fill2_k(const int* __restrict__ topkIdx, const float* __restrict__ topkW,
             const int* __restrict__ chunkBase, int* __restrict__ pairRow,
             float* __restrict__ pairW, int* __restrict__ rowPos)
{
  __shared__ int lc[NEXP];
  if (threadIdx.x < NEXP) lc[threadIdx.x] = 0;
  __syncthreads();
  const int row = blockIdx.x * 256 + threadIdx.x;
  #pragma unroll
  for (int k = 0; k < 3; ++k) {
    const int e = topkIdx[row * 3 + k];
    const int lofs = atomicAdd(&lc[e], 1);
    const int pos = chunkBase[blockIdx.x * NEXP + e] + lofs;
    pairRow[pos] = row;
    pairW[pos] = topkW[row * 3 + k];
    rowPos[row * 3 + k] = pos;
  }
}

// mix (fp16 out) = sum of the row's 3 eo slots
__global__ __launch_bounds__(256)
void mixreduce_k(const unsigned short* __restrict__ eo, const int* __restrict__ rowPos,
                 unsigned short* __restrict__ mix16)
{
  const size_t row = blockIdx.x;
  const size_t p0 = rowPos[row * 3 + 0];
  const size_t p1 = rowPos[row * 3 + 1];
  const size_t p2 = rowPos[row * 3 + 2];
  for (int c = threadIdx.x; c < EXPSZ; c += 256) {
    mix16[row * EXPSZ + c] = f2h(h2f(eo[p0 * EXPSZ + c]) + h2f(eo[p1 * EXPSZ + c])
                               + h2f(eo[p2 * EXPSZ + c]));
  }
}

__global__ __launch_bounds__(256)
void tower3_k(const unsigned short* __restrict__ t2, const float* __restrict__ tW3,
              const float* __restrict__ tb3, const int* __restrict__ taskPtr,
              float* __restrict__ out)
{
  const int t = *taskPtr;
  const float* w = tW3 + (size_t)t * 128;
  const float bias = tb3[t];
  const int lane = threadIdx.x & 63;
  const int row = blockIdx.x * 4 + (threadIdx.x >> 6);
  const unsigned short* x = t2 + (size_t)row * 128;
  float s = fmaf(h2f(x[lane]), w[lane], h2f(x[lane + 64]) * w[lane + 64]);
  #pragma unroll
  for (int o = 1; o < 64; o <<= 1) s += __shfl_xor(s, o);
  if (lane == 0) out[row] = 1.f / (1.f + expf(-(s + bias)));
  if (blockIdx.x == 0 && threadIdx.x == 0) out[BATCH] = (float)t;
}

// ---------------------------------------------------------------------------
extern "C" void kernel_launch(void* const* d_in, const int* in_sizes, int n_in,
                              void* d_out, int out_size, void* d_ws, size_t ws_size,
                              hipStream_t stream)
{
  (void)in_sizes; (void)n_in; (void)out_size; (void)ws_size;
  const float* embP  = (const float*)d_in[0];
  const float* embR  = (const float*)d_in[1];
  const float* encW1 = (const float*)d_in[2];
  const float* encB1 = (const float*)d_in[3];
  const float* ln1g  = (const float*)d_in[4];
  const float* ln1b  = (const float*)d_in[5];
  const float* encW2 = (const float*)d_in[6];
  const float* encB2 = (const float*)d_in[7];
  const float* ln2g  = (const float*)d_in[8];
  const float* ln2b  = (const float*)d_in[9];
  const float* gW1   = (const float*)d_in[10];
  const float* gb1   = (const float*)d_in[11];
  const float* gW2   = (const float*)d_in[12];
  const float* gb2   = (const float*)d_in[13];
  const float* We1   = (const float*)d_in[14];
  const float* be1   = (const float*)d_in[15];
  const float* We2   = (const float*)d_in[16];
  const float* be2   = (const float*)d_in[17];
  const float* tW1   = (const float*)d_in[18];
  const float* tb1   = (const float*)d_in[19];
  const float* tW2   = (const float*)d_in[20];
  const float* tb2   = (const float*)d_in[21];
  const float* tW3   = (const float*)d_in[22];
  const float* tb3   = (const float*)d_in[23];
  const int* taskPtr = (const int*)d_in[24];

  float* out = (float*)d_out;
  char* ws = (char*)d_ws;
  const size_t MB = 1ull << 20;

  // Lifetime-aliased workspace (peak ~209 MB):
  //  [0,64):   feat0[0,32),feat1[32,64)
  //            feat1 dead after gate -> mix16[32,48), t1f16[48,56), t2f16[56,60)
  //  [64,192): h fp32[64,192) -> We1t0[64,80),We2t0[80,88),
  //            e1b[88,136), eob[136,184)
  //  [192,208): W1t0[192,196),W1t1[196,200) -> gbuf[192,200) -> tW1t,tW2t
  //             W2t0[200,204),W2t1[204,208) -> gW1t0[200,204),gW1t1[204,208)
  //  [208,~209): metadata
  unsigned short* feat0 = (unsigned short*)(ws);
  unsigned short* feat1 = (unsigned short*)(ws + 32 * MB);
  unsigned short* mix16 = (unsigned short*)(ws + 32 * MB);
  unsigned short* t1f16 = (unsigned short*)(ws + 48 * MB);
  unsigned short* t2f16 = (unsigned short*)(ws + 56 * MB);
  float* h = (float*)(ws + 64 * MB);
  unsigned short* We1t0 = (unsigned short*)(ws + 64 * MB);
  unsigned short* We2t0 = (unsigned short*)(ws + 80 * MB);
  unsigned short* e1b   = (unsigned short*)(ws + 88 * MB);
  unsigned short* eob   = (unsigned short*)(ws + 136 * MB);
  unsigned short* W1t0  = (unsigned short*)(ws + 192 * MB);
  unsigned short* W1t1  = (unsigned short*)(ws + 196 * MB);
  unsigned short* W2t0  = (unsigned short*)(ws + 200 * MB);
  unsigned short* W2t1  = (unsigned short*)(ws + 204 * MB);
  unsigned short* gW1t0 = (unsigned short*)(ws + 200 * MB);
  unsigned short* gW1t1 = (unsigned short*)(ws + 204 * MB);
  float* gbuf = (float*)(ws + 192 * MB);
  unsigned short* tW1t = (unsigned short*)(ws + 192 * MB);
  unsigned short* tW2t = (unsigned short*)(ws + 193 * MB);
  char* small = ws + 208 * MB;
  int*   counts    = (int*)  (small);
  int*   offs      = (int*)  (small + 1024);
  int*   chunkCnt  = (int*)  (small + 2048);
  int*   chunkBase = (int*)  (small + 2048 + 4096);
  int*   topkIdx   = (int*)  (small + 16384);
  float* topkW     = (float*)(small + 16384 + 196608);
  int*   pairRow   = (int*)  (small + 16384 + 2 * 196608);
  float* pairW     = (float*)(small + 16384 + 3 * 196608);
  int*   rowPos    = (int*)  (small + 16384 + 4 * 196608);

  const dim3 blk(256, 1, 1);

  // encoder GEMM1: h = concat(embP,embR) @ W1 + b1 (reg-staged fp32 A, dbuf)
  transp_k<2,0><<<dim3(DIN/32, DHID/32, 1), blk, 0, stream>>>(encW1, W1t0, W1t1, nullptr, DIN, DHID);
  mgemm_k<1,1,3,3,32,DHID/128,0><<<dim3((BATCH/128)*(DHID/128), 1, 1), blk, 0, stream>>>(
      nullptr, nullptr, embP, embR, W1t0, W1t1, encB1, h, nullptr, nullptr,
      nullptr, nullptr, nullptr, nullptr, nullptr, BATCH, DHID, DIN);
  ln_k<DHID, true><<<dim3(BATCH, 1, 1), blk, 0, stream>>>(h, ln1g, ln1b);

  // encoder GEMM2: feat = h @ W2 + b2 (reg-staged fp32 A, dbuf) -> fp16 pair
  transp_k<2,0><<<dim3(DHID/32, DIN/32, 1), blk, 0, stream>>>(encW2, W2t0, W2t1, nullptr, DHID, DIN);
  mgemm_k<1,1,0,0,32,DIN/128,0><<<dim3((BATCH/128)*(DIN/128), 1, 1), blk, 0, stream>>>(
      nullptr, nullptr, h, nullptr, W2t0, W2t1, encB2, nullptr, feat0, feat1,
      nullptr, nullptr, nullptr, nullptr, nullptr, BATCH, DIN, DHID);
  ln_pair_k<DIN, false><<<dim3(BATCH, 1, 1), blk, 0, stream>>>(feat0, feat1, ln2g, ln2b);

  // gate: g = relu(feat @ gW1[t] + gb1[t])  (fp16 split MFMA -> fp32 gbuf)
  transp_k<2,1><<<dim3(DIN/32, 128/32, 1), blk, 0, stream>>>(gW1, gW1t0, gW1t1, taskPtr, DIN, 128);
  mgemm_k<1,0,0,4,32,1,1><<<dim3(BATCH/128, 1, 1), blk, 0, stream>>>(
      feat0, feat1, nullptr, nullptr, gW1t0, gW1t1, gb1, gbuf, nullptr, nullptr,
      nullptr, nullptr, nullptr, nullptr, taskPtr, BATCH, 128, DIN);
  gate_topk_k<<<dim3(BATCH/4, 1, 1), blk, 0, stream>>>(
      gbuf, gW2, gb2, taskPtr, out + BATCH + 1, topkIdx, topkW);
  hist_k<<<dim3(BATCH/256, 1, 1), blk, 0, stream>>>(topkIdx, chunkCnt);
  scanB_k<<<dim3(1, 1, 1), dim3(64, 1, 1), 0, stream>>>(chunkCnt, counts, offs, chunkBase);
  fill2_k<<<dim3(BATCH/256, 1, 1), blk, 0, stream>>>(topkIdx, topkW, chunkBase,
                                                     pairRow, pairW, rowPos);

  // expert weights in fp16 (h region free now)
  transp_k<1,0><<<dim3(DIN/32, EXPSZ/32, NEXP), blk, 0, stream>>>(We1, We1t0, nullptr, nullptr, DIN, EXPSZ);
  transp_k<1,0><<<dim3(EXPSZ/32, EXPSZ/32, NEXP), blk, 0, stream>>>(We2, We2t0, nullptr, nullptr, EXPSZ, EXPSZ);

  // expert GEMM1: e1 = relu(feat0[pairRow] @ We1[e] + be1)  (plain fp16, dbuf)
  mgemm_k<0,0,1,1,32,EXPSZ/128,0><<<dim3((BATCH/128)*(EXPSZ/128), 1, NEXP), blk, 0, stream>>>(
      feat0, nullptr, nullptr, nullptr, We1t0, nullptr, be1, nullptr, e1b, nullptr,
      pairRow, nullptr, counts, offs, nullptr, NPAIR, EXPSZ, DIN);
  // expert GEMM2: eo = w_p * (e1 @ We2[e] + be2)  (plain fp16, dbuf)
  mgemm_k<0,0,2,2,32,EXPSZ/128,0><<<dim3((BATCH/128)*(EXPSZ/128), 1, NEXP), blk, 0, stream>>>(
      e1b, nullptr, nullptr, nullptr, We2t0, nullptr, be2, nullptr, eob, nullptr,
      nullptr, pairW, counts, offs, nullptr, NPAIR, EXPSZ, EXPSZ);
  mixreduce_k<<<dim3(BATCH, 1, 1), blk, 0, stream>>>(eob, rowPos, mix16);

  // towers (plain fp16 MFMA, task-indexed weights/bias, dbuf)
  transp_k<1,1><<<dim3(EXPSZ/32, 256/32, 1), blk, 0, stream>>>(tW1, tW1t, nullptr, taskPtr, EXPSZ, 256);
  transp_k<1,1><<<dim3(256/32, 128/32, 1), blk, 0, stream>>>(tW2, tW2t, nullptr, taskPtr, 256, 128);
  mgemm_k<0,0,0,1,32,2,1><<<dim3((BATCH/128)*2, 1, 1), blk, 0, stream>>>(
      mix16, nullptr, nullptr, nullptr, tW1t, nullptr, tb1, nullptr, t1f16, nullptr,
      nullptr, nullptr, nullptr, nullptr, taskPtr, BATCH, 256, EXPSZ);
  mgemm_k<0,0,0,1,32,1,1><<<dim3(BATCH/128, 1, 1), blk, 0, stream>>>(
      t1f16, nullptr, nullptr, nullptr, tW2t, nullptr, tb2, nullptr, t2f16, nullptr,
      nullptr, nullptr, nullptr, nullptr, taskPtr, BATCH, 128, 256);
  tower3_k<<<dim3(BATCH/4, 1, 1), blk, 0, stream>>>(t2f16, tW3, tb3, taskPtr, out);
}